// Round 6
// baseline (464.606 us; speedup 1.0000x reference)
//
#include <hip/hip_runtime.h>
#include <hip/hip_bf16.h>

#define NN 50000
#define EE 800000
#define IN_DIM 64
#define DS_DIM 32
#define HOUT_DIM 64

// k4 chunking: 5000 waves x 160 edges; row r owns stream of C=10 edges.
#define K4_WAVES 5000
#define K4_EPW   160
#define K4_C     10

// kmega1 split: first SCAT_BLOCKS do edge scatter, rest do node encoders
#define SCAT_BLOCKS 3125   // EE/256
#define ENC_BLOCKS  6250   // NN*32/256

typedef __attribute__((ext_vector_type(8))) short bf16x8;
typedef __attribute__((ext_vector_type(4))) float f32x4;

__device__ __forceinline__ float fast_tanh(float x) {
    float xc = fminf(fmaxf(x, -15.f), 15.f);
    float e2 = __expf(2.f * xc);
    return __fdividef(e2 - 1.f, e2 + 1.f);
}

__device__ __forceinline__ void atomAddF(float* p, float v) {
#if defined(__AMDGCN__)
    unsafeAtomicAdd(p, v);
#else
    atomicAdd(p, v);
#endif
}

__device__ __forceinline__ short f2b(float f) {
    union { __hip_bfloat16 h; short s; } u;
    u.h = __float2bfloat16(f);
    return u.s;
}
__device__ __forceinline__ float b2f(unsigned short u) {
    return __uint_as_float(((unsigned int)u) << 16);
}
__device__ __forceinline__ unsigned int pack2(float lo, float hi) {
    return (unsigned int)(unsigned short)f2b(lo) | (((unsigned int)(unsigned short)f2b(hi)) << 16);
}

// KHIST: per-dst histogram + per-edge rank (atomicAdd return).
__global__ void khist(const int* __restrict__ dst, int* __restrict__ cnt, int* __restrict__ rank) {
    int e = blockIdx.x * blockDim.x + threadIdx.x;
    if (e < EE) rank[e] = atomicAdd(&cnt[dst[e]], 1);
}

// single-block exclusive scan of cnt[NN] -> rowptr[NN+1]
__global__ void __launch_bounds__(1024) kscan(const int* __restrict__ cnt, int* __restrict__ rowptr) {
    __shared__ int part[1024];
    const int T = 1024;
    const int per = (NN + T - 1) / T;
    int t = threadIdx.x;
    int lo = t * per; if (lo > NN) lo = NN;
    int hi = lo + per; if (hi > NN) hi = NN;
    int s = 0;
    for (int i = lo; i < hi; i++) s += cnt[i];
    part[t] = s;
    __syncthreads();
    for (int off = 1; off < T; off <<= 1) {
        int v = (t >= off) ? part[t - off] : 0;
        __syncthreads();
        part[t] += v;
        __syncthreads();
    }
    int run = (t == 0) ? 0 : part[t - 1];
    for (int i = lo; i < hi; i++) { rowptr[i] = run; run += cnt[i]; }
    if (t == T - 1) rowptr[NN] = run;
}

// KMEGA1: block-split fusion.
//   blocks [0, SCAT_BLOCKS): scatter edges into dst-sorted int2 list (epack).
//   blocks [SCAT_BLOCKS, +ENC_BLOCKS): h1/h2 encoders, bf16 out. thread=(node,j<32).
__global__ void kmega1(const int* __restrict__ src, const int* __restrict__ dst,
                       const int* __restrict__ rowptr, const int* __restrict__ rank,
                       int2* __restrict__ epack,
                       const float* __restrict__ x,
                       const float* __restrict__ WencP1, const float* __restrict__ bencP1,
                       const float* __restrict__ WencP2, const float* __restrict__ bencP2,
                       __hip_bfloat16* __restrict__ h1b, __hip_bfloat16* __restrict__ h2b) {
    if (blockIdx.x < SCAT_BLOCKS) {
        int e = blockIdx.x * 256 + threadIdx.x;
        int d = dst[e];
        int pos = rowptr[d] + rank[e];
        int2 p; p.x = src[e]; p.y = d;
        epack[pos] = p;
    } else {
        int tid = (blockIdx.x - SCAT_BLOCKS) * 256 + threadIdx.x;
        int n = tid >> 5;
        int j = tid & 31;
        if (n >= NN) return;
        const float* xr = x + (size_t)n * IN_DIM;
        float a1 = bencP1[j], a2 = bencP2[j];
        #pragma unroll
        for (int k = 0; k < 32; k++) {
            float q = xr[k];
            a1 = fmaf(q, WencP1[k * 32 + j], a1);
            a2 = fmaf(q, WencP2[k * 32 + j], a2);
        }
        union { __hip_bfloat16 h; short s; } u1, u2;
        u1.s = f2b(a1); u2.s = f2b(a2);
        h1b[(size_t)n * 32 + j] = u1.h;
        h2b[(size_t)n * 32 + j] = u2.h;
    }
}

// KXAGG2: fused CSR gather + linear encoders (replaces kxagg + k3a).
// Wave per node. lane = feature k of xagg. Then shuffle-broadcast matmul:
//   lane<32 : dagg[n][lane]  = sum_k xa[k]*WD[k][32+lane]   + c*bD[32+lane]
//   lane>=32: hKagg[n][l-32] = sum_k xa[32+k]*WencK[k][l-32] + c*bencK[l-32]  (bf16 out)
__global__ void __launch_bounds__(256) kxagg2(const int* __restrict__ rowptr, const int2* __restrict__ epack,
                                              const float* __restrict__ x,
                                              const float* __restrict__ WencK, const float* __restrict__ bencK,
                                              const float* __restrict__ WD, const float* __restrict__ bD,
                                              float* __restrict__ dagg, __hip_bfloat16* __restrict__ hKaggB) {
    int w = (blockIdx.x * blockDim.x + threadIdx.x) >> 6;
    int lane = threadIdx.x & 63;
    if (w >= NN) return;
    int lo = rowptr[w], hi = rowptr[w + 1];
    float acc = 0.f;
    int p = lo;
    for (; p + 1 < hi; p += 2) {
        int s0 = epack[p].x, s1 = epack[p + 1].x;
        acc += x[(size_t)s0 * 64 + lane] + x[(size_t)s1 * 64 + lane];
    }
    for (; p < hi; p++) acc += x[(size_t)epack[p].x * 64 + lane];

    float c = (float)(hi - lo);
    int jl = lane & 31;
    float outv = (lane < 32) ? c * bD[32 + jl] : c * bencK[jl];
    // k = 0..31 only feeds dagg
    #pragma unroll
    for (int k = 0; k < 32; k++) {
        float v = __shfl(acc, k);
        if (lane < 32) outv = fmaf(v, WD[k * 64 + 32 + jl], outv);
    }
    // k = 32..63 feeds both
    #pragma unroll
    for (int k = 32; k < 64; k++) {
        float v = __shfl(acc, k);
        float wv = (lane < 32) ? WD[k * 64 + 32 + jl] : WencK[(k - 32) * 32 + jl];
        outv = fmaf(v, wv, outv);
    }
    if (lane < 32) {
        dagg[(size_t)w * 32 + jl] = outv;
    } else {
        union { __hip_bfloat16 h; short s; } u;
        u.s = f2b(outv);
        hKaggB[(size_t)w * 32 + jl] = u.h;
    }
}

// K3B (MFMA node MLP): wave per 16-node tile, linear loads/stores.
__global__ void __launch_bounds__(256) k3b(
    const __hip_bfloat16* __restrict__ hKaggB, __hip_bfloat16* __restrict__ EnodeB,
    const float* __restrict__ WK1, const float* __restrict__ bK1,
    const float* __restrict__ WK2, const float* __restrict__ bK2,
    const float* __restrict__ WK3, const float* __restrict__ bK3)
{
    __shared__ float xpose[4][16 * 68];
    const int wid  = threadIdx.x >> 6;
    const int lane = threadIdx.x & 63;
    const int g = lane >> 4;
    const int r = lane & 15;
    float* xp = xpose[wid];

    bf16x8 b1[4];
    #pragma unroll
    for (int nt = 0; nt < 4; nt++) {
        #pragma unroll
        for (int i = 0; i < 8; i++)
            b1[nt][i] = f2b(WK1[(g * 8 + i) * 64 + nt * 16 + r]);
    }
    bf16x8 b2[2][4], b3[2][4];
    #pragma unroll
    for (int c = 0; c < 2; c++) {
        #pragma unroll
        for (int nt = 0; nt < 4; nt++) {
            #pragma unroll
            for (int i = 0; i < 8; i++) {
                b2[c][nt][i] = f2b(WK2[(c * 32 + g * 8 + i) * 64 + nt * 16 + r]);
                b3[c][nt][i] = f2b(WK3[(c * 32 + g * 8 + i) * 64 + nt * 16 + r]);
            }
        }
    }
    float bias1[4], bias2[4], bias3[4];
    #pragma unroll
    for (int nt = 0; nt < 4; nt++) {
        bias1[nt] = bK1[nt * 16 + r];
        bias2[nt] = bK2[nt * 16 + r];
        bias3[nt] = bK3[nt * 16 + r];
    }

    const int ntiles = NN / 16;            // 3125 exact
    const int wave = blockIdx.x * 4 + wid;
    const int nw = gridDim.x * 4;
    const f32x4 zero = {0.f, 0.f, 0.f, 0.f};

    for (int tile = wave; tile < ntiles; tile += nw) {
        bf16x8 a;
        {
            uint4 u = *reinterpret_cast<const uint4*>(hKaggB + ((size_t)tile * 16 + r) * 32 + g * 8);
            union { uint4 v; bf16x8 b; } cv; cv.v = u; a = cv.b;
        }
        f32x4 acc[4];
        #pragma unroll
        for (int nt = 0; nt < 4; nt++)
            acc[nt] = __builtin_amdgcn_mfma_f32_16x16x32_bf16(a, b1[nt], zero, 0, 0, 0);

        #pragma unroll
        for (int nt = 0; nt < 4; nt++) {
            #pragma unroll
            for (int q = 0; q < 4; q++)
                xp[(g * 4 + q) * 68 + nt * 16 + r] = fast_tanh(acc[nt][q] + bias1[nt]);
        }

        f32x4 acc2[4] = {zero, zero, zero, zero};
        #pragma unroll
        for (int c = 0; c < 2; c++) {
            const float* row = xp + r * 68 + c * 32 + g * 8;
            bf16x8 af;
            #pragma unroll
            for (int i = 0; i < 8; i++) af[i] = f2b(row[i]);
            #pragma unroll
            for (int nt = 0; nt < 4; nt++)
                acc2[nt] = __builtin_amdgcn_mfma_f32_16x16x32_bf16(af, b2[c][nt], acc2[nt], 0, 0, 0);
        }
        #pragma unroll
        for (int nt = 0; nt < 4; nt++) {
            #pragma unroll
            for (int q = 0; q < 4; q++)
                xp[(g * 4 + q) * 68 + nt * 16 + r] = fmaxf(acc2[nt][q] + bias2[nt], 0.f);
        }

        f32x4 acc3[4] = {zero, zero, zero, zero};
        #pragma unroll
        for (int c = 0; c < 2; c++) {
            const float* row = xp + r * 68 + c * 32 + g * 8;
            bf16x8 af;
            #pragma unroll
            for (int i = 0; i < 8; i++) af[i] = f2b(row[i]);
            #pragma unroll
            for (int nt = 0; nt < 4; nt++)
                acc3[nt] = __builtin_amdgcn_mfma_f32_16x16x32_bf16(af, b3[c][nt], acc3[nt], 0, 0, 0);
        }

        #pragma unroll
        for (int nt = 0; nt < 4; nt++) {
            #pragma unroll
            for (int q = 0; q < 4; q++)
                xp[(g * 4 + q) * 68 + nt * 16 + r] = acc3[nt][q] + bias3[nt];
        }
        {
            const float* row = xp + r * 68 + g * 16;
            unsigned int u[8];
            #pragma unroll
            for (int i = 0; i < 8; i++) u[i] = pack2(row[2 * i], row[2 * i + 1]);
            unsigned int* ob = reinterpret_cast<unsigned int*>(EnodeB + ((size_t)tile * 16 + r) * 64 + g * 16);
            uint4 v0 = {u[0], u[1], u[2], u[3]};
            uint4 v1 = {u[4], u[5], u[6], u[7]};
            *reinterpret_cast<uint4*>(ob) = v0;
            *reinterpret_cast<uint4*>(ob + 4) = v1;
        }
    }
}

// K4 v4 (MFMA, row-stream chunks, prefetched gathers, carry-merged scatter).
__global__ void __launch_bounds__(256) k4_mfma(
    const int2* __restrict__ epack,
    const __hip_bfloat16* __restrict__ h1b, const __hip_bfloat16* __restrict__ h2b,
    const __hip_bfloat16* __restrict__ EnodeB, float* __restrict__ Enew,
    const float* __restrict__ WU1, const float* __restrict__ bU1,
    const float* __restrict__ WU2, const float* __restrict__ bU2,
    const float* __restrict__ WU3, const float* __restrict__ bU3)
{
    __shared__ float xpose[4][16 * 68];
    const int wid  = threadIdx.x >> 6;
    const int lane = threadIdx.x & 63;
    const int g = lane >> 4;
    const int r = lane & 15;
    float* xp = xpose[wid];

    bf16x8 b1[4];
    #pragma unroll
    for (int nt = 0; nt < 4; nt++) {
        #pragma unroll
        for (int i = 0; i < 8; i++)
            b1[nt][i] = f2b(WU1[(g * 8 + i) * 64 + nt * 16 + r]);
    }
    bf16x8 b2[2][4], b3[2][4];
    #pragma unroll
    for (int c = 0; c < 2; c++) {
        #pragma unroll
        for (int nt = 0; nt < 4; nt++) {
            #pragma unroll
            for (int i = 0; i < 8; i++) {
                b2[c][nt][i] = f2b(WU2[(c * 32 + g * 8 + i) * 64 + nt * 16 + r]);
                b3[c][nt][i] = f2b(WU3[(c * 32 + g * 8 + i) * 64 + nt * 16 + r]);
            }
        }
    }
    float bias1[4], bias2[4], bias3[4];
    #pragma unroll
    for (int nt = 0; nt < 4; nt++) {
        bias1[nt] = bU1[nt * 16 + r];
        bias2[nt] = bU2[nt * 16 + r];
        bias3[nt] = bU3[nt * 16 + r];
    }

    const int wave = blockIdx.x * 4 + wid;     // [0, K4_WAVES)
    const int base = wave * K4_EPW;
    const f32x4 zero = {0.f, 0.f, 0.f, 0.f};

    int   cd[4] = {-1, -1, -1, -1};
    float cv0[4] = {0, 0, 0, 0}, cv1[4] = {0, 0, 0, 0},
          cv2[4] = {0, 0, 0, 0}, cv3[4] = {0, 0, 0, 0};

    // prefetch t=0
    int2 ep = epack[base + r * K4_C];
    uint4 v1 = *reinterpret_cast<const uint4*>(h1b + (size_t)ep.x * 32 + g * 8);
    uint4 v2 = *reinterpret_cast<const uint4*>(h2b + (size_t)ep.y * 32 + g * 8);

    for (int t = 0; t < K4_C; t++) {
        const int s_me = ep.x, d_me = ep.y;
        union { uint4 v; unsigned int u[4]; } u1, u2;
        u1.v = v1; u2.v = v2;
        // prefetch t+1 (independent -> hides under tile-t compute)
        if (t + 1 < K4_C) {
            ep = epack[base + r * K4_C + t + 1];
            v1 = *reinterpret_cast<const uint4*>(h1b + (size_t)ep.x * 32 + g * 8);
            v2 = *reinterpret_cast<const uint4*>(h2b + (size_t)ep.y * 32 + g * 8);
        }

        bf16x8 a;
        #pragma unroll
        for (int w = 0; w < 4; w++) {
            float lo = b2f((unsigned short)(u1.u[w] & 0xffff)) + b2f((unsigned short)(u2.u[w] & 0xffff));
            float hi = b2f((unsigned short)(u1.u[w] >> 16))    + b2f((unsigned short)(u2.u[w] >> 16));
            a[2 * w]     = f2b(lo);
            a[2 * w + 1] = f2b(hi);
        }
        f32x4 acc[4];
        #pragma unroll
        for (int nt = 0; nt < 4; nt++)
            acc[nt] = __builtin_amdgcn_mfma_f32_16x16x32_bf16(a, b1[nt], zero, 0, 0, 0);

        #pragma unroll
        for (int nt = 0; nt < 4; nt++) {
            #pragma unroll
            for (int q = 0; q < 4; q++)
                xp[(g * 4 + q) * 68 + nt * 16 + r] = fast_tanh(acc[nt][q] + bias1[nt]);
        }

        f32x4 acc2[4] = {zero, zero, zero, zero};
        #pragma unroll
        for (int c = 0; c < 2; c++) {
            const float* row = xp + r * 68 + c * 32 + g * 8;
            bf16x8 af;
            #pragma unroll
            for (int i = 0; i < 8; i++) af[i] = f2b(row[i]);
            #pragma unroll
            for (int nt = 0; nt < 4; nt++)
                acc2[nt] = __builtin_amdgcn_mfma_f32_16x16x32_bf16(af, b2[c][nt], acc2[nt], 0, 0, 0);
        }
        #pragma unroll
        for (int nt = 0; nt < 4; nt++) {
            #pragma unroll
            for (int q = 0; q < 4; q++)
                xp[(g * 4 + q) * 68 + nt * 16 + r] = fmaxf(acc2[nt][q] + bias2[nt], 0.f);
        }

        f32x4 acc3[4] = {zero, zero, zero, zero};
        #pragma unroll
        for (int c = 0; c < 2; c++) {
            const float* row = xp + r * 68 + c * 32 + g * 8;
            bf16x8 af;
            #pragma unroll
            for (int i = 0; i < 8; i++) af[i] = f2b(row[i]);
            #pragma unroll
            for (int nt = 0; nt < 4; nt++)
                acc3[nt] = __builtin_amdgcn_mfma_f32_16x16x32_bf16(af, b3[c][nt], acc3[nt], 0, 0, 0);
        }

        #pragma unroll
        for (int q = 0; q < 4; q++) {
            const int er = g * 4 + q;
            const int ssv = __shfl(s_me, er);
            const int dqv = __shfl(d_me, er);
            const unsigned short* enp = reinterpret_cast<const unsigned short*>(EnodeB) + (size_t)ssv * 64 + r;
            float w0 = (acc3[0][q] + bias3[0]) * b2f(enp[0]);
            float w1 = (acc3[1][q] + bias3[1]) * b2f(enp[16]);
            float w2 = (acc3[2][q] + bias3[2]) * b2f(enp[32]);
            float w3 = (acc3[3][q] + bias3[3]) * b2f(enp[48]);
            if (dqv == cd[q]) {
                cv0[q] += w0; cv1[q] += w1; cv2[q] += w2; cv3[q] += w3;
            } else {
                if (cd[q] >= 0) {
                    float* ew = Enew + (size_t)cd[q] * 64 + r;
                    atomAddF(ew,      cv0[q]);
                    atomAddF(ew + 16, cv1[q]);
                    atomAddF(ew + 32, cv2[q]);
                    atomAddF(ew + 48, cv3[q]);
                }
                cd[q] = dqv;
                cv0[q] = w0; cv1[q] = w1; cv2[q] = w2; cv3[q] = w3;
            }
        }
    }
    #pragma unroll
    for (int q = 0; q < 4; q++) {
        if (cd[q] >= 0) {
            float* ew = Enew + (size_t)cd[q] * 64 + r;
            atomAddF(ew,      cv0[q]);
            atomAddF(ew + 16, cv1[q]);
            atomAddF(ew + 32, cv2[q]);
            atomAddF(ew + 48, cv3[q]);
        }
    }
}

// K5: dH = E_new @ WH + bH ; out = [dH[:,32:], -dH[:,:32] - dagg]
__global__ void k5_out(const float* __restrict__ Enew, const float* __restrict__ dagg,
                       const float* __restrict__ WH, const float* __restrict__ bH,
                       float* __restrict__ out) {
    int tid = blockIdx.x * blockDim.x + threadIdx.x;
    int n = tid >> 6;
    int j = tid & 63;
    if (n >= NN) return;
    const float* er = Enew + (size_t)n * 64;
    int jj = (j < 32) ? (j + 32) : (j - 32);
    float acc = bH[jj];
    #pragma unroll
    for (int k = 0; k < 64; k++) acc = fmaf(er[k], WH[k * 64 + jj], acc);
    float val;
    if (j < 32) val = acc;
    else        val = -acc - dagg[(size_t)n * 32 + (j - 32)];
    out[tid] = val;
}

extern "C" void kernel_launch(void* const* d_in, const int* in_sizes, int n_in,
                              void* d_out, int out_size, void* d_ws, size_t ws_size,
                              hipStream_t stream) {
    const float* x      = (const float*)d_in[0];
    const int*   src    = (const int*)d_in[1];
    const int*   dst    = (const int*)d_in[2];
    const float* WencK  = (const float*)d_in[3];
    const float* bencK  = (const float*)d_in[4];
    const float* WencP1 = (const float*)d_in[5];
    const float* bencP1 = (const float*)d_in[6];
    const float* WencP2 = (const float*)d_in[7];
    const float* bencP2 = (const float*)d_in[8];
    const float* WK1    = (const float*)d_in[9];
    const float* bK1    = (const float*)d_in[10];
    const float* WK2    = (const float*)d_in[11];
    const float* bK2    = (const float*)d_in[12];
    const float* WK3    = (const float*)d_in[13];
    const float* bK3    = (const float*)d_in[14];
    const float* WU1    = (const float*)d_in[15];
    const float* bU1    = (const float*)d_in[16];
    const float* WU2    = (const float*)d_in[17];
    const float* bU2    = (const float*)d_in[18];
    const float* WU3    = (const float*)d_in[19];
    const float* bU3    = (const float*)d_in[20];
    const float* WH     = (const float*)d_in[21];
    const float* bH     = (const float*)d_in[22];
    const float* WD     = (const float*)d_in[23];
    const float* bD     = (const float*)d_in[24];
    float* out = (float*)d_out;

    // ---- workspace layout ----
    float* Enew = (float*)d_ws;                                  // NN*64 f32
    float* dagg = Enew + (size_t)NN * 64;                        // NN*32 f32
    __hip_bfloat16* h1b    = (__hip_bfloat16*)(dagg + (size_t)NN * 32);  // NN*32 bf16
    __hip_bfloat16* h2b    = h1b + (size_t)NN * 32;              // NN*32 bf16
    __hip_bfloat16* EnodeB = h2b + (size_t)NN * 32;              // NN*64 bf16
    __hip_bfloat16* hKaggB = EnodeB + (size_t)NN * 64;           // NN*32 bf16
    int*  cnt    = (int*)(hKaggB + (size_t)NN * 32);             // NN
    int*  rowptr = cnt + NN;                                     // NN+1
    int*  rank   = rowptr + NN + 1;                              // EE
    int2* epack  = (int2*)(rank + EE);                           // EE int2
    size_t need = (size_t)NN * 96 * 4 + (size_t)NN * 160 * 2
                + ((size_t)NN * 2 + 1 + (size_t)EE * 3) * 4;
    if (ws_size < need) return;

    hipMemsetAsync(cnt, 0, (size_t)NN * sizeof(int), stream);
    hipMemsetAsync(Enew, 0, (size_t)NN * 64 * sizeof(float), stream);

    khist<<<(EE + 255) / 256, 256, 0, stream>>>(dst, cnt, rank);
    kscan<<<1, 1024, 0, stream>>>(cnt, rowptr);
    kmega1<<<SCAT_BLOCKS + ENC_BLOCKS, 256, 0, stream>>>(
        src, dst, rowptr, rank, epack, x, WencP1, bencP1, WencP2, bencP2, h1b, h2b);
    kxagg2<<<(NN * 64 + 255) / 256, 256, 0, stream>>>(rowptr, epack, x, WencK, bencK, WD, bD, dagg, hKaggB);
    k3b<<<782, 256, 0, stream>>>(hKaggB, EnodeB, WK1, bK1, WK2, bK2, WK3, bK3);
    k4_mfma<<<K4_WAVES / 4, 256, 0, stream>>>(epack, h1b, h2b, EnodeB, Enew,
                                              WU1, bU1, WU2, bU2, WU3, bU3);
    k5_out<<<(NN * 64 + 255) / 256, 256, 0, stream>>>(Enew, dagg, WH, bH, out);
}

// Round 7
// 457.275 us; speedup vs baseline: 1.0160x; 1.0160x over previous
//
#include <hip/hip_runtime.h>
#include <hip/hip_bf16.h>

#define NN 50000
#define EE 800000
#define IN_DIM 64
#define DS_DIM 32
#define HOUT_DIM 64

// k4 chunking: 5000 waves x 160 edges; row r owns stream of C=10 edges.
#define K4_WAVES 5000
#define K4_EPW   160
#define K4_C     10

// kxagg3 chunking: 12500 waves x 64 edges
#define XA_EPW 64

// kmega1 split: first SCAT_BLOCKS do edge scatter, rest do node encoders
#define SCAT_BLOCKS 3125   // EE/256
#define ENC_BLOCKS  6250   // NN*32/256

typedef __attribute__((ext_vector_type(8))) short bf16x8;
typedef __attribute__((ext_vector_type(4))) float f32x4;

__device__ __forceinline__ float fast_tanh(float x) {
    float xc = fminf(fmaxf(x, -15.f), 15.f);
    float e2 = __expf(2.f * xc);
    return __fdividef(e2 - 1.f, e2 + 1.f);
}

__device__ __forceinline__ void atomAddF(float* p, float v) {
#if defined(__AMDGCN__)
    unsafeAtomicAdd(p, v);
#else
    atomicAdd(p, v);
#endif
}

__device__ __forceinline__ short f2b(float f) {
    union { __hip_bfloat16 h; short s; } u;
    u.h = __float2bfloat16(f);
    return u.s;
}
__device__ __forceinline__ float b2f(unsigned short u) {
    return __uint_as_float(((unsigned int)u) << 16);
}
__device__ __forceinline__ unsigned int pack2(float lo, float hi) {
    return (unsigned int)(unsigned short)f2b(lo) | (((unsigned int)(unsigned short)f2b(hi)) << 16);
}

// KHIST: per-dst histogram + per-edge rank (atomicAdd return).
__global__ void khist(const int* __restrict__ dst, int* __restrict__ cnt, int* __restrict__ rank) {
    int e = blockIdx.x * blockDim.x + threadIdx.x;
    if (e < EE) rank[e] = atomicAdd(&cnt[dst[e]], 1);
}

// single-block exclusive scan of cnt[NN] -> rowptr[NN+1]
__global__ void __launch_bounds__(1024) kscan(const int* __restrict__ cnt, int* __restrict__ rowptr) {
    __shared__ int part[1024];
    const int T = 1024;
    const int per = (NN + T - 1) / T;
    int t = threadIdx.x;
    int lo = t * per; if (lo > NN) lo = NN;
    int hi = lo + per; if (hi > NN) hi = NN;
    int s = 0;
    for (int i = lo; i < hi; i++) s += cnt[i];
    part[t] = s;
    __syncthreads();
    for (int off = 1; off < T; off <<= 1) {
        int v = (t >= off) ? part[t - off] : 0;
        __syncthreads();
        part[t] += v;
        __syncthreads();
    }
    int run = (t == 0) ? 0 : part[t - 1];
    for (int i = lo; i < hi; i++) { rowptr[i] = run; run += cnt[i]; }
    if (t == T - 1) rowptr[NN] = run;
}

// KMEGA1: block-split fusion.
//   blocks [0, SCAT_BLOCKS): scatter edges into dst-sorted int2 list (epack).
//   blocks [SCAT_BLOCKS, +ENC_BLOCKS): h1/h2 encoders, bf16 out. thread=(node,j<32).
__global__ void kmega1(const int* __restrict__ src, const int* __restrict__ dst,
                       const int* __restrict__ rowptr, const int* __restrict__ rank,
                       int2* __restrict__ epack,
                       const float* __restrict__ x,
                       const float* __restrict__ WencP1, const float* __restrict__ bencP1,
                       const float* __restrict__ WencP2, const float* __restrict__ bencP2,
                       __hip_bfloat16* __restrict__ h1b, __hip_bfloat16* __restrict__ h2b) {
    if (blockIdx.x < SCAT_BLOCKS) {
        int e = blockIdx.x * 256 + threadIdx.x;
        int d = dst[e];
        int pos = rowptr[d] + rank[e];
        int2 p; p.x = src[e]; p.y = d;
        epack[pos] = p;
    } else {
        int tid = (blockIdx.x - SCAT_BLOCKS) * 256 + threadIdx.x;
        int n = tid >> 5;
        int j = tid & 31;
        if (n >= NN) return;
        const float* xr = x + (size_t)n * IN_DIM;
        float a1 = bencP1[j], a2 = bencP2[j];
        #pragma unroll
        for (int k = 0; k < 32; k++) {
            float q = xr[k];
            a1 = fmaf(q, WencP1[k * 32 + j], a1);
            a2 = fmaf(q, WencP2[k * 32 + j], a2);
        }
        union { __hip_bfloat16 h; short s; } u1, u2;
        u1.s = f2b(a1); u2.s = f2b(a2);
        h1b[(size_t)n * 32 + j] = u1.h;
        h2b[(size_t)n * 32 + j] = u2.h;
    }
}

// KXAGG3: edge-chunk carry-merged segment-sum of x rows into xagg.
// Wave walks 64 consecutive dst-sorted edges; lane = feature; atomic row-flush
// only at dst-run boundaries. t+1 prefetch hides gather latency.
__global__ void __launch_bounds__(256) kxagg3(const int2* __restrict__ epack,
                                              const float* __restrict__ x,
                                              float* __restrict__ xagg) {
    int w = (blockIdx.x * blockDim.x + threadIdx.x) >> 6;
    int lane = threadIdx.x & 63;
    int base = w * XA_EPW;

    int2 ep = epack[base];
    float v = x[(size_t)ep.x * 64 + lane];
    int cd = ep.y;
    float carry = 0.f;
    #pragma unroll 4
    for (int t = 0; t < XA_EPW; t++) {
        int d = ep.y;
        float cur = v;
        if (t + 1 < XA_EPW) {
            ep = epack[base + t + 1];
            v = x[(size_t)ep.x * 64 + lane];
        }
        if (d == cd) {
            carry += cur;
        } else {
            atomAddF(&xagg[(size_t)cd * 64 + lane], carry);
            cd = d;
            carry = cur;
        }
    }
    atomAddF(&xagg[(size_t)cd * 64 + lane], carry);
}

// K3A: thread = (node, j<64). j<32: dagg col j. j>=32: hKagg col (j-32) -> bf16.
//   dagg  = xagg @ WD[:,32:] + cnt*bD[32:]
//   hKagg = xagg[:,32:] @ WencK + cnt*bencK
__global__ void k3a(const float* __restrict__ xagg, const int* __restrict__ cnt,
                    const float* __restrict__ WencK, const float* __restrict__ bencK,
                    const float* __restrict__ WD, const float* __restrict__ bD,
                    float* __restrict__ dagg, __hip_bfloat16* __restrict__ hKaggB) {
    int tid = blockIdx.x * blockDim.x + threadIdx.x;
    int n = tid >> 6;
    int j = tid & 63;
    if (n >= NN) return;
    const float* xa = xagg + (size_t)n * 64;
    float c = (float)cnt[n];
    if (j < 32) {
        float acc = c * bD[32 + j];
        #pragma unroll
        for (int k = 0; k < 64; k++) acc = fmaf(xa[k], WD[k * 64 + 32 + j], acc);
        dagg[(size_t)n * 32 + j] = acc;
    } else {
        int jj = j - 32;
        float acc = c * bencK[jj];
        #pragma unroll
        for (int k = 0; k < 32; k++) acc = fmaf(xa[32 + k], WencK[k * 32 + jj], acc);
        union { __hip_bfloat16 h; short s; } u;
        u.s = f2b(acc);
        hKaggB[(size_t)n * 32 + jj] = u.h;
    }
}

// K3B (MFMA node MLP): wave per 16-node tile, linear loads/stores.
__global__ void __launch_bounds__(256) k3b(
    const __hip_bfloat16* __restrict__ hKaggB, __hip_bfloat16* __restrict__ EnodeB,
    const float* __restrict__ WK1, const float* __restrict__ bK1,
    const float* __restrict__ WK2, const float* __restrict__ bK2,
    const float* __restrict__ WK3, const float* __restrict__ bK3)
{
    __shared__ float xpose[4][16 * 68];
    const int wid  = threadIdx.x >> 6;
    const int lane = threadIdx.x & 63;
    const int g = lane >> 4;
    const int r = lane & 15;
    float* xp = xpose[wid];

    bf16x8 b1[4];
    #pragma unroll
    for (int nt = 0; nt < 4; nt++) {
        #pragma unroll
        for (int i = 0; i < 8; i++)
            b1[nt][i] = f2b(WK1[(g * 8 + i) * 64 + nt * 16 + r]);
    }
    bf16x8 b2[2][4], b3[2][4];
    #pragma unroll
    for (int c = 0; c < 2; c++) {
        #pragma unroll
        for (int nt = 0; nt < 4; nt++) {
            #pragma unroll
            for (int i = 0; i < 8; i++) {
                b2[c][nt][i] = f2b(WK2[(c * 32 + g * 8 + i) * 64 + nt * 16 + r]);
                b3[c][nt][i] = f2b(WK3[(c * 32 + g * 8 + i) * 64 + nt * 16 + r]);
            }
        }
    }
    float bias1[4], bias2[4], bias3[4];
    #pragma unroll
    for (int nt = 0; nt < 4; nt++) {
        bias1[nt] = bK1[nt * 16 + r];
        bias2[nt] = bK2[nt * 16 + r];
        bias3[nt] = bK3[nt * 16 + r];
    }

    const int ntiles = NN / 16;            // 3125 exact
    const int wave = blockIdx.x * 4 + wid;
    const int nw = gridDim.x * 4;
    const f32x4 zero = {0.f, 0.f, 0.f, 0.f};

    for (int tile = wave; tile < ntiles; tile += nw) {
        bf16x8 a;
        {
            uint4 u = *reinterpret_cast<const uint4*>(hKaggB + ((size_t)tile * 16 + r) * 32 + g * 8);
            union { uint4 v; bf16x8 b; } cv; cv.v = u; a = cv.b;
        }
        f32x4 acc[4];
        #pragma unroll
        for (int nt = 0; nt < 4; nt++)
            acc[nt] = __builtin_amdgcn_mfma_f32_16x16x32_bf16(a, b1[nt], zero, 0, 0, 0);

        #pragma unroll
        for (int nt = 0; nt < 4; nt++) {
            #pragma unroll
            for (int q = 0; q < 4; q++)
                xp[(g * 4 + q) * 68 + nt * 16 + r] = fast_tanh(acc[nt][q] + bias1[nt]);
        }

        f32x4 acc2[4] = {zero, zero, zero, zero};
        #pragma unroll
        for (int c = 0; c < 2; c++) {
            const float* row = xp + r * 68 + c * 32 + g * 8;
            bf16x8 af;
            #pragma unroll
            for (int i = 0; i < 8; i++) af[i] = f2b(row[i]);
            #pragma unroll
            for (int nt = 0; nt < 4; nt++)
                acc2[nt] = __builtin_amdgcn_mfma_f32_16x16x32_bf16(af, b2[c][nt], acc2[nt], 0, 0, 0);
        }
        #pragma unroll
        for (int nt = 0; nt < 4; nt++) {
            #pragma unroll
            for (int q = 0; q < 4; q++)
                xp[(g * 4 + q) * 68 + nt * 16 + r] = fmaxf(acc2[nt][q] + bias2[nt], 0.f);
        }

        f32x4 acc3[4] = {zero, zero, zero, zero};
        #pragma unroll
        for (int c = 0; c < 2; c++) {
            const float* row = xp + r * 68 + c * 32 + g * 8;
            bf16x8 af;
            #pragma unroll
            for (int i = 0; i < 8; i++) af[i] = f2b(row[i]);
            #pragma unroll
            for (int nt = 0; nt < 4; nt++)
                acc3[nt] = __builtin_amdgcn_mfma_f32_16x16x32_bf16(af, b3[c][nt], acc3[nt], 0, 0, 0);
        }

        #pragma unroll
        for (int nt = 0; nt < 4; nt++) {
            #pragma unroll
            for (int q = 0; q < 4; q++)
                xp[(g * 4 + q) * 68 + nt * 16 + r] = acc3[nt][q] + bias3[nt];
        }
        {
            const float* row = xp + r * 68 + g * 16;
            unsigned int u[8];
            #pragma unroll
            for (int i = 0; i < 8; i++) u[i] = pack2(row[2 * i], row[2 * i + 1]);
            unsigned int* ob = reinterpret_cast<unsigned int*>(EnodeB + ((size_t)tile * 16 + r) * 64 + g * 16);
            uint4 v0 = {u[0], u[1], u[2], u[3]};
            uint4 v1 = {u[4], u[5], u[6], u[7]};
            *reinterpret_cast<uint4*>(ob) = v0;
            *reinterpret_cast<uint4*>(ob + 4) = v1;
        }
    }
}

// K4 v4 (MFMA, row-stream chunks, prefetched gathers, carry-merged scatter).
__global__ void __launch_bounds__(256) k4_mfma(
    const int2* __restrict__ epack,
    const __hip_bfloat16* __restrict__ h1b, const __hip_bfloat16* __restrict__ h2b,
    const __hip_bfloat16* __restrict__ EnodeB, float* __restrict__ Enew,
    const float* __restrict__ WU1, const float* __restrict__ bU1,
    const float* __restrict__ WU2, const float* __restrict__ bU2,
    const float* __restrict__ WU3, const float* __restrict__ bU3)
{
    __shared__ float xpose[4][16 * 68];
    const int wid  = threadIdx.x >> 6;
    const int lane = threadIdx.x & 63;
    const int g = lane >> 4;
    const int r = lane & 15;
    float* xp = xpose[wid];

    bf16x8 b1[4];
    #pragma unroll
    for (int nt = 0; nt < 4; nt++) {
        #pragma unroll
        for (int i = 0; i < 8; i++)
            b1[nt][i] = f2b(WU1[(g * 8 + i) * 64 + nt * 16 + r]);
    }
    bf16x8 b2[2][4], b3[2][4];
    #pragma unroll
    for (int c = 0; c < 2; c++) {
        #pragma unroll
        for (int nt = 0; nt < 4; nt++) {
            #pragma unroll
            for (int i = 0; i < 8; i++) {
                b2[c][nt][i] = f2b(WU2[(c * 32 + g * 8 + i) * 64 + nt * 16 + r]);
                b3[c][nt][i] = f2b(WU3[(c * 32 + g * 8 + i) * 64 + nt * 16 + r]);
            }
        }
    }
    float bias1[4], bias2[4], bias3[4];
    #pragma unroll
    for (int nt = 0; nt < 4; nt++) {
        bias1[nt] = bU1[nt * 16 + r];
        bias2[nt] = bU2[nt * 16 + r];
        bias3[nt] = bU3[nt * 16 + r];
    }

    const int wave = blockIdx.x * 4 + wid;     // [0, K4_WAVES)
    const int base = wave * K4_EPW;
    const f32x4 zero = {0.f, 0.f, 0.f, 0.f};

    int   cd[4] = {-1, -1, -1, -1};
    float cv0[4] = {0, 0, 0, 0}, cv1[4] = {0, 0, 0, 0},
          cv2[4] = {0, 0, 0, 0}, cv3[4] = {0, 0, 0, 0};

    // prefetch t=0
    int2 ep = epack[base + r * K4_C];
    uint4 v1 = *reinterpret_cast<const uint4*>(h1b + (size_t)ep.x * 32 + g * 8);
    uint4 v2 = *reinterpret_cast<const uint4*>(h2b + (size_t)ep.y * 32 + g * 8);

    for (int t = 0; t < K4_C; t++) {
        const int s_me = ep.x, d_me = ep.y;
        union { uint4 v; unsigned int u[4]; } u1, u2;
        u1.v = v1; u2.v = v2;
        // prefetch t+1 (independent -> hides under tile-t compute)
        if (t + 1 < K4_C) {
            ep = epack[base + r * K4_C + t + 1];
            v1 = *reinterpret_cast<const uint4*>(h1b + (size_t)ep.x * 32 + g * 8);
            v2 = *reinterpret_cast<const uint4*>(h2b + (size_t)ep.y * 32 + g * 8);
        }

        bf16x8 a;
        #pragma unroll
        for (int w = 0; w < 4; w++) {
            float lo = b2f((unsigned short)(u1.u[w] & 0xffff)) + b2f((unsigned short)(u2.u[w] & 0xffff));
            float hi = b2f((unsigned short)(u1.u[w] >> 16))    + b2f((unsigned short)(u2.u[w] >> 16));
            a[2 * w]     = f2b(lo);
            a[2 * w + 1] = f2b(hi);
        }
        f32x4 acc[4];
        #pragma unroll
        for (int nt = 0; nt < 4; nt++)
            acc[nt] = __builtin_amdgcn_mfma_f32_16x16x32_bf16(a, b1[nt], zero, 0, 0, 0);

        #pragma unroll
        for (int nt = 0; nt < 4; nt++) {
            #pragma unroll
            for (int q = 0; q < 4; q++)
                xp[(g * 4 + q) * 68 + nt * 16 + r] = fast_tanh(acc[nt][q] + bias1[nt]);
        }

        f32x4 acc2[4] = {zero, zero, zero, zero};
        #pragma unroll
        for (int c = 0; c < 2; c++) {
            const float* row = xp + r * 68 + c * 32 + g * 8;
            bf16x8 af;
            #pragma unroll
            for (int i = 0; i < 8; i++) af[i] = f2b(row[i]);
            #pragma unroll
            for (int nt = 0; nt < 4; nt++)
                acc2[nt] = __builtin_amdgcn_mfma_f32_16x16x32_bf16(af, b2[c][nt], acc2[nt], 0, 0, 0);
        }
        #pragma unroll
        for (int nt = 0; nt < 4; nt++) {
            #pragma unroll
            for (int q = 0; q < 4; q++)
                xp[(g * 4 + q) * 68 + nt * 16 + r] = fmaxf(acc2[nt][q] + bias2[nt], 0.f);
        }

        f32x4 acc3[4] = {zero, zero, zero, zero};
        #pragma unroll
        for (int c = 0; c < 2; c++) {
            const float* row = xp + r * 68 + c * 32 + g * 8;
            bf16x8 af;
            #pragma unroll
            for (int i = 0; i < 8; i++) af[i] = f2b(row[i]);
            #pragma unroll
            for (int nt = 0; nt < 4; nt++)
                acc3[nt] = __builtin_amdgcn_mfma_f32_16x16x32_bf16(af, b3[c][nt], acc3[nt], 0, 0, 0);
        }

        #pragma unroll
        for (int q = 0; q < 4; q++) {
            const int er = g * 4 + q;
            const int ssv = __shfl(s_me, er);
            const int dqv = __shfl(d_me, er);
            const unsigned short* enp = reinterpret_cast<const unsigned short*>(EnodeB) + (size_t)ssv * 64 + r;
            float w0 = (acc3[0][q] + bias3[0]) * b2f(enp[0]);
            float w1 = (acc3[1][q] + bias3[1]) * b2f(enp[16]);
            float w2 = (acc3[2][q] + bias3[2]) * b2f(enp[32]);
            float w3 = (acc3[3][q] + bias3[3]) * b2f(enp[48]);
            if (dqv == cd[q]) {
                cv0[q] += w0; cv1[q] += w1; cv2[q] += w2; cv3[q] += w3;
            } else {
                if (cd[q] >= 0) {
                    float* ew = Enew + (size_t)cd[q] * 64 + r;
                    atomAddF(ew,      cv0[q]);
                    atomAddF(ew + 16, cv1[q]);
                    atomAddF(ew + 32, cv2[q]);
                    atomAddF(ew + 48, cv3[q]);
                }
                cd[q] = dqv;
                cv0[q] = w0; cv1[q] = w1; cv2[q] = w2; cv3[q] = w3;
            }
        }
    }
    #pragma unroll
    for (int q = 0; q < 4; q++) {
        if (cd[q] >= 0) {
            float* ew = Enew + (size_t)cd[q] * 64 + r;
            atomAddF(ew,      cv0[q]);
            atomAddF(ew + 16, cv1[q]);
            atomAddF(ew + 32, cv2[q]);
            atomAddF(ew + 48, cv3[q]);
        }
    }
}

// K5: dH = E_new @ WH + bH ; out = [dH[:,32:], -dH[:,:32] - dagg]
__global__ void k5_out(const float* __restrict__ Enew, const float* __restrict__ dagg,
                       const float* __restrict__ WH, const float* __restrict__ bH,
                       float* __restrict__ out) {
    int tid = blockIdx.x * blockDim.x + threadIdx.x;
    int n = tid >> 6;
    int j = tid & 63;
    if (n >= NN) return;
    const float* er = Enew + (size_t)n * 64;
    int jj = (j < 32) ? (j + 32) : (j - 32);
    float acc = bH[jj];
    #pragma unroll
    for (int k = 0; k < 64; k++) acc = fmaf(er[k], WH[k * 64 + jj], acc);
    float val;
    if (j < 32) val = acc;
    else        val = -acc - dagg[(size_t)n * 32 + (j - 32)];
    out[tid] = val;
}

extern "C" void kernel_launch(void* const* d_in, const int* in_sizes, int n_in,
                              void* d_out, int out_size, void* d_ws, size_t ws_size,
                              hipStream_t stream) {
    const float* x      = (const float*)d_in[0];
    const int*   src    = (const int*)d_in[1];
    const int*   dst    = (const int*)d_in[2];
    const float* WencK  = (const float*)d_in[3];
    const float* bencK  = (const float*)d_in[4];
    const float* WencP1 = (const float*)d_in[5];
    const float* bencP1 = (const float*)d_in[6];
    const float* WencP2 = (const float*)d_in[7];
    const float* bencP2 = (const float*)d_in[8];
    const float* WK1    = (const float*)d_in[9];
    const float* bK1    = (const float*)d_in[10];
    const float* WK2    = (const float*)d_in[11];
    const float* bK2    = (const float*)d_in[12];
    const float* WK3    = (const float*)d_in[13];
    const float* bK3    = (const float*)d_in[14];
    const float* WU1    = (const float*)d_in[15];
    const float* bU1    = (const float*)d_in[16];
    const float* WU2    = (const float*)d_in[17];
    const float* bU2    = (const float*)d_in[18];
    const float* WU3    = (const float*)d_in[19];
    const float* bU3    = (const float*)d_in[20];
    const float* WH     = (const float*)d_in[21];
    const float* bH     = (const float*)d_in[22];
    const float* WD     = (const float*)d_in[23];
    const float* bD     = (const float*)d_in[24];
    float* out = (float*)d_out;

    // ---- workspace layout (58.0 MB <= proven-available 64 MB) ----
    float* Enew = (float*)d_ws;                                  // NN*64 f32
    float* xagg = Enew + (size_t)NN * 64;                        // NN*64 f32 (contiguous w/ Enew for one memset)
    float* dagg = xagg + (size_t)NN * 64;                        // NN*32 f32
    __hip_bfloat16* h1b    = (__hip_bfloat16*)(dagg + (size_t)NN * 32);  // NN*32 bf16
    __hip_bfloat16* h2b    = h1b + (size_t)NN * 32;              // NN*32 bf16
    __hip_bfloat16* EnodeB = h2b + (size_t)NN * 32;              // NN*64 bf16
    __hip_bfloat16* hKaggB = EnodeB + (size_t)NN * 64;           // NN*32 bf16
    int*  cnt    = (int*)(hKaggB + (size_t)NN * 32);             // NN
    int*  rowptr = cnt + NN;                                     // NN+2 (padded for epack 8B alignment)
    int*  rank   = rowptr + NN + 2;                              // EE
    int2* epack  = (int2*)(rank + EE);                           // EE int2 (8B-aligned)
    size_t need = (size_t)NN * 160 * 4 + (size_t)NN * 160 * 2
                + ((size_t)NN * 2 + 2 + (size_t)EE) * 4 + (size_t)EE * 8;
    if (ws_size < need) return;

    hipMemsetAsync(cnt, 0, (size_t)NN * sizeof(int), stream);
    hipMemsetAsync(Enew, 0, (size_t)NN * 128 * sizeof(float), stream);  // Enew + xagg

    khist<<<(EE + 255) / 256, 256, 0, stream>>>(dst, cnt, rank);
    kscan<<<1, 1024, 0, stream>>>(cnt, rowptr);
    kmega1<<<SCAT_BLOCKS + ENC_BLOCKS, 256, 0, stream>>>(
        src, dst, rowptr, rank, epack, x, WencP1, bencP1, WencP2, bencP2, h1b, h2b);
    kxagg3<<<(EE / XA_EPW) / 4, 256, 0, stream>>>(epack, x, xagg);
    k3a<<<(NN * 64 + 255) / 256, 256, 0, stream>>>(xagg, cnt, WencK, bencK, WD, bD, dagg, hKaggB);
    k3b<<<782, 256, 0, stream>>>(hKaggB, EnodeB, WK1, bK1, WK2, bK2, WK3, bK3);
    k4_mfma<<<K4_WAVES / 4, 256, 0, stream>>>(epack, h1b, h2b, EnodeB, Enew,
                                              WU1, bU1, WU2, bU2, WU3, bU3);
    k5_out<<<(NN * 64 + 255) / 256, 256, 0, stream>>>(Enew, dagg, WH, bH, out);
}

// Round 8
// 423.027 us; speedup vs baseline: 1.0983x; 1.0810x over previous
//
#include <hip/hip_runtime.h>
#include <hip/hip_bf16.h>

#define NN 50000
#define EE 800000
#define IN_DIM 64
#define DS_DIM 32
#define HOUT_DIM 64

// k4 chunking: 10000 waves x 80 edges; row r owns stream of C=5 edges.
#define K4_WAVES 10000
#define K4_EPW   80
#define K4_C     5

// kxagg3 chunking: 12500 waves x 64 edges
#define XA_EPW 64

// kmega1 split: first SCAT_BLOCKS do edge scatter, rest do node encoders
#define SCAT_BLOCKS 3125   // EE/256
#define ENC_BLOCKS  6250   // NN*32/256

// scan blocks
#define SCAN_NB 196        // ceil(NN/256)

typedef __attribute__((ext_vector_type(8))) short bf16x8;
typedef __attribute__((ext_vector_type(4))) float f32x4;

__device__ __forceinline__ float fast_tanh(float x) {
    // 1 - 2/(exp2(x*2log2e)+1): saturates to +-1 without clamps (inf-safe).
    float e = __builtin_amdgcn_exp2f(x * 2.885390082f);
    return 1.f - 2.f * __builtin_amdgcn_rcpf(e + 1.f);
}

__device__ __forceinline__ void atomAddF(float* p, float v) {
#if defined(__AMDGCN__)
    unsafeAtomicAdd(p, v);
#else
    atomicAdd(p, v);
#endif
}

__device__ __forceinline__ short f2b(float f) {
    union { __hip_bfloat16 h; short s; } u;
    u.h = __float2bfloat16(f);
    return u.s;
}
__device__ __forceinline__ float b2f(unsigned short u) {
    return __uint_as_float(((unsigned int)u) << 16);
}
__device__ __forceinline__ unsigned int pack2(float lo, float hi) {
    return (unsigned int)(unsigned short)f2b(lo) | (((unsigned int)(unsigned short)f2b(hi)) << 16);
}

// KHIST: per-dst histogram.
__global__ void khist(const int* __restrict__ dst, int* __restrict__ cnt) {
    int e = blockIdx.x * blockDim.x + threadIdx.x;
    if (e < EE) atomicAdd(&cnt[dst[e]], 1);
}

// 3-phase coalesced exclusive scan of cnt[NN] -> rowptr[NN+1]
__global__ void kscanA(const int* __restrict__ cnt, int* __restrict__ blocksum) {
    __shared__ int s[256];
    int t = threadIdx.x;
    int i = blockIdx.x * 256 + t;
    s[t] = (i < NN) ? cnt[i] : 0;
    __syncthreads();
    #pragma unroll
    for (int off = 128; off > 0; off >>= 1) {
        if (t < off) s[t] += s[t + off];
        __syncthreads();
    }
    if (t == 0) blocksum[blockIdx.x] = s[0];
}

__global__ void kscanB(const int* __restrict__ blocksum, int* __restrict__ blockoff) {
    __shared__ int part[256];
    int t = threadIdx.x;
    int v = (t < SCAN_NB) ? blocksum[t] : 0;
    part[t] = v;
    __syncthreads();
    for (int off = 1; off < 256; off <<= 1) {
        int u = (t >= off) ? part[t - off] : 0;
        __syncthreads();
        part[t] += u;
        __syncthreads();
    }
    if (t < SCAN_NB) blockoff[t] = part[t] - v;  // exclusive
}

__global__ void kscanC(const int* __restrict__ cnt, const int* __restrict__ blockoff,
                       int* __restrict__ rowptr) {
    __shared__ int part[256];
    int t = threadIdx.x;
    int i = blockIdx.x * 256 + t;
    int v = (i < NN) ? cnt[i] : 0;
    part[t] = v;
    __syncthreads();
    for (int off = 1; off < 256; off <<= 1) {
        int u = (t >= off) ? part[t - off] : 0;
        __syncthreads();
        part[t] += u;
        __syncthreads();
    }
    if (i < NN) {
        int incl = blockoff[blockIdx.x] + part[t];
        rowptr[i] = incl - v;
        if (i == NN - 1) rowptr[NN] = incl;
    }
}

// KMEGA1: block-split fusion.
//   blocks [0, SCAT_BLOCKS): scatter edges into dst-sorted int2 list (epack),
//     deriving rank via atomic fill.
//   blocks [SCAT_BLOCKS, +ENC_BLOCKS): h1/h2 encoders (bf16) + bf16 x copy.
__global__ void kmega1(const int* __restrict__ src, const int* __restrict__ dst,
                       const int* __restrict__ rowptr, int* __restrict__ fill,
                       int2* __restrict__ epack,
                       const float* __restrict__ x,
                       const float* __restrict__ WencP1, const float* __restrict__ bencP1,
                       const float* __restrict__ WencP2, const float* __restrict__ bencP2,
                       __hip_bfloat16* __restrict__ h1b, __hip_bfloat16* __restrict__ h2b,
                       __hip_bfloat16* __restrict__ xb) {
    if (blockIdx.x < SCAT_BLOCKS) {
        int e = blockIdx.x * 256 + threadIdx.x;
        int d = dst[e];
        int pos = rowptr[d] + atomicAdd(&fill[d], 1);
        int2 p; p.x = src[e]; p.y = d;
        epack[pos] = p;
    } else {
        int tid = (blockIdx.x - SCAT_BLOCKS) * 256 + threadIdx.x;
        int n = tid >> 5;
        int j = tid & 31;
        if (n >= NN) return;
        const float* xr = x + (size_t)n * IN_DIM;
        float a1 = bencP1[j], a2 = bencP2[j];
        #pragma unroll
        for (int k = 0; k < 32; k++) {
            float q = xr[k];
            a1 = fmaf(q, WencP1[k * 32 + j], a1);
            a2 = fmaf(q, WencP2[k * 32 + j], a2);
        }
        union { __hip_bfloat16 h; short s; } u1, u2, u3, u4;
        u1.s = f2b(a1); u2.s = f2b(a2);
        h1b[(size_t)n * 32 + j] = u1.h;
        h2b[(size_t)n * 32 + j] = u2.h;
        u3.s = f2b(xr[j]); u4.s = f2b(xr[32 + j]);
        xb[(size_t)n * 64 + j] = u3.h;
        xb[(size_t)n * 64 + 32 + j] = u4.h;
    }
}

// KXAGG3: edge-chunk carry-merged segment-sum of bf16 x rows into xagg (f32).
__global__ void __launch_bounds__(256) kxagg3(const int2* __restrict__ epack,
                                              const __hip_bfloat16* __restrict__ xb,
                                              float* __restrict__ xagg) {
    int w = (blockIdx.x * blockDim.x + threadIdx.x) >> 6;
    int lane = threadIdx.x & 63;
    int base = w * XA_EPW;
    const unsigned short* xu = reinterpret_cast<const unsigned short*>(xb);

    int2 ep = epack[base];
    float v = b2f(xu[(size_t)ep.x * 64 + lane]);
    int cd = ep.y;
    float carry = 0.f;
    #pragma unroll 4
    for (int t = 0; t < XA_EPW; t++) {
        int d = ep.y;
        float cur = v;
        if (t + 1 < XA_EPW) {
            ep = epack[base + t + 1];
            v = b2f(xu[(size_t)ep.x * 64 + lane]);
        }
        if (d == cd) {
            carry += cur;
        } else {
            atomAddF(&xagg[(size_t)cd * 64 + lane], carry);
            cd = d;
            carry = cur;
        }
    }
    atomAddF(&xagg[(size_t)cd * 64 + lane], carry);
}

// K3A: thread = (node, j<64). j<32: dagg col j. j>=32: hKagg col (j-32) -> bf16.
__global__ void k3a(const float* __restrict__ xagg, const int* __restrict__ cnt,
                    const float* __restrict__ WencK, const float* __restrict__ bencK,
                    const float* __restrict__ WD, const float* __restrict__ bD,
                    float* __restrict__ dagg, __hip_bfloat16* __restrict__ hKaggB) {
    int tid = blockIdx.x * blockDim.x + threadIdx.x;
    int n = tid >> 6;
    int j = tid & 63;
    if (n >= NN) return;
    const float* xa = xagg + (size_t)n * 64;
    float c = (float)cnt[n];
    if (j < 32) {
        float acc = c * bD[32 + j];
        #pragma unroll
        for (int k = 0; k < 64; k++) acc = fmaf(xa[k], WD[k * 64 + 32 + j], acc);
        dagg[(size_t)n * 32 + j] = acc;
    } else {
        int jj = j - 32;
        float acc = c * bencK[jj];
        #pragma unroll
        for (int k = 0; k < 32; k++) acc = fmaf(xa[32 + k], WencK[k * 32 + jj], acc);
        union { __hip_bfloat16 h; short s; } u;
        u.s = f2b(acc);
        hKaggB[(size_t)n * 32 + jj] = u.h;
    }
}

// K3B (MFMA node MLP): wave per 16-node tile, linear loads/stores.
__global__ void __launch_bounds__(256) k3b(
    const __hip_bfloat16* __restrict__ hKaggB, __hip_bfloat16* __restrict__ EnodeB,
    const float* __restrict__ WK1, const float* __restrict__ bK1,
    const float* __restrict__ WK2, const float* __restrict__ bK2,
    const float* __restrict__ WK3, const float* __restrict__ bK3)
{
    __shared__ float xpose[4][16 * 68];
    const int wid  = threadIdx.x >> 6;
    const int lane = threadIdx.x & 63;
    const int g = lane >> 4;
    const int r = lane & 15;
    float* xp = xpose[wid];

    bf16x8 b1[4];
    #pragma unroll
    for (int nt = 0; nt < 4; nt++) {
        #pragma unroll
        for (int i = 0; i < 8; i++)
            b1[nt][i] = f2b(WK1[(g * 8 + i) * 64 + nt * 16 + r]);
    }
    bf16x8 b2[2][4], b3[2][4];
    #pragma unroll
    for (int c = 0; c < 2; c++) {
        #pragma unroll
        for (int nt = 0; nt < 4; nt++) {
            #pragma unroll
            for (int i = 0; i < 8; i++) {
                b2[c][nt][i] = f2b(WK2[(c * 32 + g * 8 + i) * 64 + nt * 16 + r]);
                b3[c][nt][i] = f2b(WK3[(c * 32 + g * 8 + i) * 64 + nt * 16 + r]);
            }
        }
    }
    float bias1[4], bias2[4], bias3[4];
    #pragma unroll
    for (int nt = 0; nt < 4; nt++) {
        bias1[nt] = bK1[nt * 16 + r];
        bias2[nt] = bK2[nt * 16 + r];
        bias3[nt] = bK3[nt * 16 + r];
    }

    const int ntiles = NN / 16;            // 3125 exact
    const int wave = blockIdx.x * 4 + wid;
    const int nw = gridDim.x * 4;
    const f32x4 zero = {0.f, 0.f, 0.f, 0.f};

    for (int tile = wave; tile < ntiles; tile += nw) {
        bf16x8 a;
        {
            uint4 u = *reinterpret_cast<const uint4*>(hKaggB + ((size_t)tile * 16 + r) * 32 + g * 8);
            union { uint4 v; bf16x8 b; } cv; cv.v = u; a = cv.b;
        }
        f32x4 acc[4];
        #pragma unroll
        for (int nt = 0; nt < 4; nt++)
            acc[nt] = __builtin_amdgcn_mfma_f32_16x16x32_bf16(a, b1[nt], zero, 0, 0, 0);

        #pragma unroll
        for (int nt = 0; nt < 4; nt++) {
            #pragma unroll
            for (int q = 0; q < 4; q++)
                xp[(g * 4 + q) * 68 + nt * 16 + r] = fast_tanh(acc[nt][q] + bias1[nt]);
        }

        f32x4 acc2[4] = {zero, zero, zero, zero};
        #pragma unroll
        for (int c = 0; c < 2; c++) {
            const float* row = xp + r * 68 + c * 32 + g * 8;
            bf16x8 af;
            #pragma unroll
            for (int i = 0; i < 8; i++) af[i] = f2b(row[i]);
            #pragma unroll
            for (int nt = 0; nt < 4; nt++)
                acc2[nt] = __builtin_amdgcn_mfma_f32_16x16x32_bf16(af, b2[c][nt], acc2[nt], 0, 0, 0);
        }
        #pragma unroll
        for (int nt = 0; nt < 4; nt++) {
            #pragma unroll
            for (int q = 0; q < 4; q++)
                xp[(g * 4 + q) * 68 + nt * 16 + r] = fmaxf(acc2[nt][q] + bias2[nt], 0.f);
        }

        f32x4 acc3[4] = {zero, zero, zero, zero};
        #pragma unroll
        for (int c = 0; c < 2; c++) {
            const float* row = xp + r * 68 + c * 32 + g * 8;
            bf16x8 af;
            #pragma unroll
            for (int i = 0; i < 8; i++) af[i] = f2b(row[i]);
            #pragma unroll
            for (int nt = 0; nt < 4; nt++)
                acc3[nt] = __builtin_amdgcn_mfma_f32_16x16x32_bf16(af, b3[c][nt], acc3[nt], 0, 0, 0);
        }

        #pragma unroll
        for (int nt = 0; nt < 4; nt++) {
            #pragma unroll
            for (int q = 0; q < 4; q++)
                xp[(g * 4 + q) * 68 + nt * 16 + r] = acc3[nt][q] + bias3[nt];
        }
        {
            const float* row = xp + r * 68 + g * 16;
            unsigned int u[8];
            #pragma unroll
            for (int i = 0; i < 8; i++) u[i] = pack2(row[2 * i], row[2 * i + 1]);
            unsigned int* ob = reinterpret_cast<unsigned int*>(EnodeB + ((size_t)tile * 16 + r) * 64 + g * 16);
            uint4 v0 = {u[0], u[1], u[2], u[3]};
            uint4 v1 = {u[4], u[5], u[6], u[7]};
            *reinterpret_cast<uint4*>(ob) = v0;
            *reinterpret_cast<uint4*>(ob + 4) = v1;
        }
    }
}

// K4 v5 (MFMA, row-stream chunks, prefetched gathers, carry-merged scatter, setprio).
__global__ void __launch_bounds__(256) k4_mfma(
    const int2* __restrict__ epack,
    const __hip_bfloat16* __restrict__ h1b, const __hip_bfloat16* __restrict__ h2b,
    const __hip_bfloat16* __restrict__ EnodeB, float* __restrict__ Enew,
    const float* __restrict__ WU1, const float* __restrict__ bU1,
    const float* __restrict__ WU2, const float* __restrict__ bU2,
    const float* __restrict__ WU3, const float* __restrict__ bU3)
{
    __shared__ float xpose[4][16 * 68];
    const int wid  = threadIdx.x >> 6;
    const int lane = threadIdx.x & 63;
    const int g = lane >> 4;
    const int r = lane & 15;
    float* xp = xpose[wid];

    bf16x8 b1[4];
    #pragma unroll
    for (int nt = 0; nt < 4; nt++) {
        #pragma unroll
        for (int i = 0; i < 8; i++)
            b1[nt][i] = f2b(WU1[(g * 8 + i) * 64 + nt * 16 + r]);
    }
    bf16x8 b2[2][4], b3[2][4];
    #pragma unroll
    for (int c = 0; c < 2; c++) {
        #pragma unroll
        for (int nt = 0; nt < 4; nt++) {
            #pragma unroll
            for (int i = 0; i < 8; i++) {
                b2[c][nt][i] = f2b(WU2[(c * 32 + g * 8 + i) * 64 + nt * 16 + r]);
                b3[c][nt][i] = f2b(WU3[(c * 32 + g * 8 + i) * 64 + nt * 16 + r]);
            }
        }
    }
    float bias1[4], bias2[4], bias3[4];
    #pragma unroll
    for (int nt = 0; nt < 4; nt++) {
        bias1[nt] = bU1[nt * 16 + r];
        bias2[nt] = bU2[nt * 16 + r];
        bias3[nt] = bU3[nt * 16 + r];
    }

    const int wave = blockIdx.x * 4 + wid;     // [0, K4_WAVES)
    const int base = wave * K4_EPW;
    const f32x4 zero = {0.f, 0.f, 0.f, 0.f};

    int   cd[4] = {-1, -1, -1, -1};
    float cv0[4] = {0, 0, 0, 0}, cv1[4] = {0, 0, 0, 0},
          cv2[4] = {0, 0, 0, 0}, cv3[4] = {0, 0, 0, 0};

    // prefetch t=0
    int2 ep = epack[base + r * K4_C];
    uint4 v1 = *reinterpret_cast<const uint4*>(h1b + (size_t)ep.x * 32 + g * 8);
    uint4 v2 = *reinterpret_cast<const uint4*>(h2b + (size_t)ep.y * 32 + g * 8);

    for (int t = 0; t < K4_C; t++) {
        const int s_me = ep.x, d_me = ep.y;
        union { uint4 v; unsigned int u[4]; } u1, u2;
        u1.v = v1; u2.v = v2;
        // prefetch t+1 (independent -> hides under tile-t compute)
        if (t + 1 < K4_C) {
            ep = epack[base + r * K4_C + t + 1];
            v1 = *reinterpret_cast<const uint4*>(h1b + (size_t)ep.x * 32 + g * 8);
            v2 = *reinterpret_cast<const uint4*>(h2b + (size_t)ep.y * 32 + g * 8);
        }

        bf16x8 a;
        #pragma unroll
        for (int w = 0; w < 4; w++) {
            float lo = b2f((unsigned short)(u1.u[w] & 0xffff)) + b2f((unsigned short)(u2.u[w] & 0xffff));
            float hi = b2f((unsigned short)(u1.u[w] >> 16))    + b2f((unsigned short)(u2.u[w] >> 16));
            a[2 * w]     = f2b(lo);
            a[2 * w + 1] = f2b(hi);
        }
        __builtin_amdgcn_s_setprio(1);
        f32x4 acc[4];
        #pragma unroll
        for (int nt = 0; nt < 4; nt++)
            acc[nt] = __builtin_amdgcn_mfma_f32_16x16x32_bf16(a, b1[nt], zero, 0, 0, 0);

        #pragma unroll
        for (int nt = 0; nt < 4; nt++) {
            #pragma unroll
            for (int q = 0; q < 4; q++)
                xp[(g * 4 + q) * 68 + nt * 16 + r] = fast_tanh(acc[nt][q] + bias1[nt]);
        }

        f32x4 acc2[4] = {zero, zero, zero, zero};
        #pragma unroll
        for (int c = 0; c < 2; c++) {
            const float* row = xp + r * 68 + c * 32 + g * 8;
            bf16x8 af;
            #pragma unroll
            for (int i = 0; i < 8; i++) af[i] = f2b(row[i]);
            #pragma unroll
            for (int nt = 0; nt < 4; nt++)
                acc2[nt] = __builtin_amdgcn_mfma_f32_16x16x32_bf16(af, b2[c][nt], acc2[nt], 0, 0, 0);
        }
        #pragma unroll
        for (int nt = 0; nt < 4; nt++) {
            #pragma unroll
            for (int q = 0; q < 4; q++)
                xp[(g * 4 + q) * 68 + nt * 16 + r] = fmaxf(acc2[nt][q] + bias2[nt], 0.f);
        }

        f32x4 acc3[4] = {zero, zero, zero, zero};
        #pragma unroll
        for (int c = 0; c < 2; c++) {
            const float* row = xp + r * 68 + c * 32 + g * 8;
            bf16x8 af;
            #pragma unroll
            for (int i = 0; i < 8; i++) af[i] = f2b(row[i]);
            #pragma unroll
            for (int nt = 0; nt < 4; nt++)
                acc3[nt] = __builtin_amdgcn_mfma_f32_16x16x32_bf16(af, b3[c][nt], acc3[nt], 0, 0, 0);
        }
        __builtin_amdgcn_s_setprio(0);

        #pragma unroll
        for (int q = 0; q < 4; q++) {
            const int er = g * 4 + q;
            const int ssv = __shfl(s_me, er);
            const int dqv = __shfl(d_me, er);
            const unsigned short* enp = reinterpret_cast<const unsigned short*>(EnodeB) + (size_t)ssv * 64 + r;
            float w0 = (acc3[0][q] + bias3[0]) * b2f(enp[0]);
            float w1 = (acc3[1][q] + bias3[1]) * b2f(enp[16]);
            float w2 = (acc3[2][q] + bias3[2]) * b2f(enp[32]);
            float w3 = (acc3[3][q] + bias3[3]) * b2f(enp[48]);
            if (dqv == cd[q]) {
                cv0[q] += w0; cv1[q] += w1; cv2[q] += w2; cv3[q] += w3;
            } else {
                if (cd[q] >= 0) {
                    float* ew = Enew + (size_t)cd[q] * 64 + r;
                    atomAddF(ew,      cv0[q]);
                    atomAddF(ew + 16, cv1[q]);
                    atomAddF(ew + 32, cv2[q]);
                    atomAddF(ew + 48, cv3[q]);
                }
                cd[q] = dqv;
                cv0[q] = w0; cv1[q] = w1; cv2[q] = w2; cv3[q] = w3;
            }
        }
    }
    #pragma unroll
    for (int q = 0; q < 4; q++) {
        if (cd[q] >= 0) {
            float* ew = Enew + (size_t)cd[q] * 64 + r;
            atomAddF(ew,      cv0[q]);
            atomAddF(ew + 16, cv1[q]);
            atomAddF(ew + 32, cv2[q]);
            atomAddF(ew + 48, cv3[q]);
        }
    }
}

// K5: dH = E_new @ WH + bH ; out = [dH[:,32:], -dH[:,:32] - dagg]
__global__ void k5_out(const float* __restrict__ Enew, const float* __restrict__ dagg,
                       const float* __restrict__ WH, const float* __restrict__ bH,
                       float* __restrict__ out) {
    int tid = blockIdx.x * blockDim.x + threadIdx.x;
    int n = tid >> 6;
    int j = tid & 63;
    if (n >= NN) return;
    const float* er = Enew + (size_t)n * 64;
    int jj = (j < 32) ? (j + 32) : (j - 32);
    float acc = bH[jj];
    #pragma unroll
    for (int k = 0; k < 64; k++) acc = fmaf(er[k], WH[k * 64 + jj], acc);
    float val;
    if (j < 32) val = acc;
    else        val = -acc - dagg[(size_t)n * 32 + (j - 32)];
    out[tid] = val;
}

extern "C" void kernel_launch(void* const* d_in, const int* in_sizes, int n_in,
                              void* d_out, int out_size, void* d_ws, size_t ws_size,
                              hipStream_t stream) {
    const float* x      = (const float*)d_in[0];
    const int*   src    = (const int*)d_in[1];
    const int*   dst    = (const int*)d_in[2];
    const float* WencK  = (const float*)d_in[3];
    const float* bencK  = (const float*)d_in[4];
    const float* WencP1 = (const float*)d_in[5];
    const float* bencP1 = (const float*)d_in[6];
    const float* WencP2 = (const float*)d_in[7];
    const float* bencP2 = (const float*)d_in[8];
    const float* WK1    = (const float*)d_in[9];
    const float* bK1    = (const float*)d_in[10];
    const float* WK2    = (const float*)d_in[11];
    const float* bK2    = (const float*)d_in[12];
    const float* WK3    = (const float*)d_in[13];
    const float* bK3    = (const float*)d_in[14];
    const float* WU1    = (const float*)d_in[15];
    const float* bU1    = (const float*)d_in[16];
    const float* WU2    = (const float*)d_in[17];
    const float* bU2    = (const float*)d_in[18];
    const float* WU3    = (const float*)d_in[19];
    const float* bU3    = (const float*)d_in[20];
    const float* WH     = (const float*)d_in[21];
    const float* bH     = (const float*)d_in[22];
    const float* WD     = (const float*)d_in[23];
    const float* bD     = (const float*)d_in[24];
    float* out = (float*)d_out;

    // ---- workspace layout (~48.6 MB) ----
    float* buf0 = (float*)d_ws;                                  // NN*64 f32: xagg, later Enew
    float* dagg = buf0 + (size_t)NN * 64;                        // NN*32 f32
    __hip_bfloat16* h1b    = (__hip_bfloat16*)(dagg + (size_t)NN * 32);  // NN*32 bf16
    __hip_bfloat16* h2b    = h1b + (size_t)NN * 32;              // NN*32 bf16
    __hip_bfloat16* EnodeB = h2b + (size_t)NN * 32;              // NN*64 bf16
    __hip_bfloat16* hKaggB = EnodeB + (size_t)NN * 64;           // NN*32 bf16
    __hip_bfloat16* xb     = hKaggB + (size_t)NN * 32;           // NN*64 bf16
    int*  cnt      = (int*)(xb + (size_t)NN * 64);               // NN
    int*  fill     = cnt + NN;                                   // NN
    int*  rowptr   = fill + NN;                                  // NN+2 (pad)
    int*  blocksum = rowptr + NN + 2;                            // 256
    int*  blockoff = blocksum + 256;                             // 256
    int2* epack    = (int2*)(blockoff + 256);                    // EE int2 (8B aligned)
    size_t need = (size_t)NN * 96 * 4 + (size_t)NN * 224 * 2
                + ((size_t)NN * 3 + 2 + 512) * 4 + (size_t)EE * 8;
    if (ws_size < need) return;

    hipMemsetAsync(cnt, 0, (size_t)2 * NN * sizeof(int), stream);           // cnt + fill
    hipMemsetAsync(buf0, 0, (size_t)NN * 64 * sizeof(float), stream);       // xagg

    khist<<<(EE + 255) / 256, 256, 0, stream>>>(dst, cnt);
    kscanA<<<SCAN_NB, 256, 0, stream>>>(cnt, blocksum);
    kscanB<<<1, 256, 0, stream>>>(blocksum, blockoff);
    kscanC<<<SCAN_NB, 256, 0, stream>>>(cnt, blockoff, rowptr);
    kmega1<<<SCAT_BLOCKS + ENC_BLOCKS, 256, 0, stream>>>(
        src, dst, rowptr, fill, epack, x, WencP1, bencP1, WencP2, bencP2, h1b, h2b, xb);
    kxagg3<<<(EE / XA_EPW) / 4, 256, 0, stream>>>(epack, xb, buf0);
    k3a<<<(NN * 64 + 255) / 256, 256, 0, stream>>>(buf0, cnt, WencK, bencK, WD, bD, dagg, hKaggB);
    // xagg dead -> reuse buf0 as Enew
    hipMemsetAsync(buf0, 0, (size_t)NN * 64 * sizeof(float), stream);
    k3b<<<782, 256, 0, stream>>>(hKaggB, EnodeB, WK1, bK1, WK2, bK2, WK3, bK3);
    k4_mfma<<<K4_WAVES / 4, 256, 0, stream>>>(epack, h1b, h2b, EnodeB, buf0,
                                              WU1, bU1, WU2, bU2, WU3, bU3);
    k5_out<<<(NN * 64 + 255) / 256, 256, 0, stream>>>(buf0, dagg, WH, bH, out);
}

// Round 9
// 294.950 us; speedup vs baseline: 1.5752x; 1.4342x over previous
//
#include <hip/hip_runtime.h>
#include <hip/hip_bf16.h>

#define NN 50000
#define EE 800000
#define IN_DIM 64
#define DS_DIM 32
#define HOUT_DIM 64

// k4 chunking: 10000 waves x 80 edges; row r owns stream of C=5 edges.
#define K4_WAVES 10000
#define K4_EPW   80
#define K4_C     5

// kxagg3 chunking: 12500 waves x 64 edges
#define XA_EPW 64

// kmega1 split: first SCAT_BLOCKS do edge scatter, rest do node encoders
#define SCAT_BLOCKS 3125   // EE/256
#define ENC_BLOCKS  6250   // NN*32/256

// scan blocks
#define SCAN_NB 196        // ceil(NN/256)

typedef __attribute__((ext_vector_type(8))) short bf16x8;
typedef __attribute__((ext_vector_type(4))) float f32x4;

__device__ __forceinline__ float fast_tanh(float x) {
    // 1 - 2/(exp2(x*2log2e)+1): saturates to +-1 without clamps (inf-safe).
    float e = __builtin_amdgcn_exp2f(x * 2.885390082f);
    return 1.f - 2.f * __builtin_amdgcn_rcpf(e + 1.f);
}

__device__ __forceinline__ void atomAddF(float* p, float v) {
#if defined(__AMDGCN__)
    unsafeAtomicAdd(p, v);
#else
    atomicAdd(p, v);
#endif
}

__device__ __forceinline__ short f2b(float f) {
    union { __hip_bfloat16 h; short s; } u;
    u.h = __float2bfloat16(f);
    return u.s;
}
__device__ __forceinline__ float b2f(unsigned short u) {
    return __uint_as_float(((unsigned int)u) << 16);
}
__device__ __forceinline__ unsigned int pack2(float lo, float hi) {
    return (unsigned int)(unsigned short)f2b(lo) | (((unsigned int)(unsigned short)f2b(hi)) << 16);
}

// KHIST: per-dst histogram.
__global__ void khist(const int* __restrict__ dst, int* __restrict__ cnt) {
    int e = blockIdx.x * blockDim.x + threadIdx.x;
    if (e < EE) atomicAdd(&cnt[dst[e]], 1);
}

// 3-phase coalesced exclusive scan of cnt[NN] -> rowptr[NN+1]
__global__ void kscanA(const int* __restrict__ cnt, int* __restrict__ blocksum) {
    __shared__ int s[256];
    int t = threadIdx.x;
    int i = blockIdx.x * 256 + t;
    s[t] = (i < NN) ? cnt[i] : 0;
    __syncthreads();
    #pragma unroll
    for (int off = 128; off > 0; off >>= 1) {
        if (t < off) s[t] += s[t + off];
        __syncthreads();
    }
    if (t == 0) blocksum[blockIdx.x] = s[0];
}

__global__ void kscanB(const int* __restrict__ blocksum, int* __restrict__ blockoff) {
    __shared__ int part[256];
    int t = threadIdx.x;
    int v = (t < SCAN_NB) ? blocksum[t] : 0;
    part[t] = v;
    __syncthreads();
    for (int off = 1; off < 256; off <<= 1) {
        int u = (t >= off) ? part[t - off] : 0;
        __syncthreads();
        part[t] += u;
        __syncthreads();
    }
    if (t < SCAN_NB) blockoff[t] = part[t] - v;  // exclusive
}

__global__ void kscanC(const int* __restrict__ cnt, const int* __restrict__ blockoff,
                       int* __restrict__ rowptr) {
    __shared__ int part[256];
    int t = threadIdx.x;
    int i = blockIdx.x * 256 + t;
    int v = (i < NN) ? cnt[i] : 0;
    part[t] = v;
    __syncthreads();
    for (int off = 1; off < 256; off <<= 1) {
        int u = (t >= off) ? part[t - off] : 0;
        __syncthreads();
        part[t] += u;
        __syncthreads();
    }
    if (i < NN) {
        int incl = blockoff[blockIdx.x] + part[t];
        rowptr[i] = incl - v;
        if (i == NN - 1) rowptr[NN] = incl;
    }
}

// KMEGA1: block-split fusion.
//   blocks [0, SCAT_BLOCKS): scatter edges into dst-sorted int2 list (epack),
//     deriving rank via atomic fill.
//   blocks [SCAT_BLOCKS, +ENC_BLOCKS): h1/h2 encoders (bf16) + bf16 x copy.
__global__ void kmega1(const int* __restrict__ src, const int* __restrict__ dst,
                       const int* __restrict__ rowptr, int* __restrict__ fill,
                       int2* __restrict__ epack,
                       const float* __restrict__ x,
                       const float* __restrict__ WencP1, const float* __restrict__ bencP1,
                       const float* __restrict__ WencP2, const float* __restrict__ bencP2,
                       __hip_bfloat16* __restrict__ h1b, __hip_bfloat16* __restrict__ h2b,
                       __hip_bfloat16* __restrict__ xb) {
    if (blockIdx.x < SCAT_BLOCKS) {
        int e = blockIdx.x * 256 + threadIdx.x;
        int d = dst[e];
        int pos = rowptr[d] + atomicAdd(&fill[d], 1);
        int2 p; p.x = src[e]; p.y = d;
        epack[pos] = p;
    } else {
        int tid = (blockIdx.x - SCAT_BLOCKS) * 256 + threadIdx.x;
        int n = tid >> 5;
        int j = tid & 31;
        if (n >= NN) return;
        const float* xr = x + (size_t)n * IN_DIM;
        float a1 = bencP1[j], a2 = bencP2[j];
        #pragma unroll
        for (int k = 0; k < 32; k++) {
            float q = xr[k];
            a1 = fmaf(q, WencP1[k * 32 + j], a1);
            a2 = fmaf(q, WencP2[k * 32 + j], a2);
        }
        union { __hip_bfloat16 h; short s; } u1, u2, u3, u4;
        u1.s = f2b(a1); u2.s = f2b(a2);
        h1b[(size_t)n * 32 + j] = u1.h;
        h2b[(size_t)n * 32 + j] = u2.h;
        u3.s = f2b(xr[j]); u4.s = f2b(xr[32 + j]);
        xb[(size_t)n * 64 + j] = u3.h;
        xb[(size_t)n * 64 + 32 + j] = u4.h;
    }
}

// KXAGG3 v2: edge-chunk carry-merged segment-sum of bf16 x rows into xagg (f32).
// Lane t holds epack entry t (one coalesced load); 4-deep gather pipeline.
__global__ void __launch_bounds__(256) kxagg3(const int2* __restrict__ epack,
                                              const __hip_bfloat16* __restrict__ xb,
                                              float* __restrict__ xagg) {
    int w = (blockIdx.x * blockDim.x + threadIdx.x) >> 6;
    int lane = threadIdx.x & 63;
    int base = w * XA_EPW;
    const unsigned short* xu = reinterpret_cast<const unsigned short*>(xb);

    int2 myep = epack[base + lane];     // coalesced 512B per wave
    int sarr = myep.x, darr = myep.y;

    float v0 = b2f(xu[(size_t)__shfl(sarr, 0) * 64 + lane]);
    float v1 = b2f(xu[(size_t)__shfl(sarr, 1) * 64 + lane]);
    float v2 = b2f(xu[(size_t)__shfl(sarr, 2) * 64 + lane]);
    float v3 = b2f(xu[(size_t)__shfl(sarr, 3) * 64 + lane]);
    int cd = __shfl(darr, 0);
    float carry = 0.f;

#define XA_STEP(vv, T)                                                        \
    {                                                                         \
        float cur = vv;                                                       \
        if ((T) + 4 < XA_EPW)                                                 \
            vv = b2f(xu[(size_t)__shfl(sarr, (T) + 4) * 64 + lane]);          \
        int d = __shfl(darr, (T));                                            \
        if (d != cd) {                                                        \
            atomAddF(&xagg[(size_t)cd * 64 + lane], carry);                   \
            cd = d; carry = 0.f;                                              \
        }                                                                     \
        carry += cur;                                                         \
    }

    for (int tb = 0; tb < XA_EPW; tb += 4) {
        XA_STEP(v0, tb);
        XA_STEP(v1, tb + 1);
        XA_STEP(v2, tb + 2);
        XA_STEP(v3, tb + 3);
    }
#undef XA_STEP
    atomAddF(&xagg[(size_t)cd * 64 + lane], carry);
}

// K3AB (fused): per 16-node tile compute dagg (MFMA), hKagg (MFMA, stays in
// LDS), then the 3-layer node MLP -> EnodeB. Replaces k3a + k3b.
__global__ void __launch_bounds__(256) k3ab(
    const float* __restrict__ xagg, const int* __restrict__ cnt,
    const float* __restrict__ WencK, const float* __restrict__ bencK,
    const float* __restrict__ WD, const float* __restrict__ bD,
    const float* __restrict__ WK1, const float* __restrict__ bK1,
    const float* __restrict__ WK2, const float* __restrict__ bK2,
    const float* __restrict__ WK3, const float* __restrict__ bK3,
    float* __restrict__ dagg, __hip_bfloat16* __restrict__ EnodeB)
{
    __shared__ float xpose[4][16 * 68];
    const int wid  = threadIdx.x >> 6;
    const int lane = threadIdx.x & 63;
    const int g = lane >> 4;
    const int r = lane & 15;
    float* xp = xpose[wid];

    // --- weight fragments ---
    bf16x8 bwd[2][2];   // WD[:,32+...]: [kchunk][ntile(2)]
    #pragma unroll
    for (int c = 0; c < 2; c++)
        #pragma unroll
        for (int nd = 0; nd < 2; nd++)
            #pragma unroll
            for (int i = 0; i < 8; i++)
                bwd[c][nd][i] = f2b(WD[(c * 32 + g * 8 + i) * 64 + 32 + nd * 16 + r]);
    bf16x8 bwk[2];      // WencK: [ntile(2)]
    #pragma unroll
    for (int nd = 0; nd < 2; nd++)
        #pragma unroll
        for (int i = 0; i < 8; i++)
            bwk[nd][i] = f2b(WencK[(g * 8 + i) * 32 + nd * 16 + r]);
    bf16x8 b1[4];
    #pragma unroll
    for (int nt = 0; nt < 4; nt++)
        #pragma unroll
        for (int i = 0; i < 8; i++)
            b1[nt][i] = f2b(WK1[(g * 8 + i) * 64 + nt * 16 + r]);
    bf16x8 b2[2][4], b3[2][4];
    #pragma unroll
    for (int c = 0; c < 2; c++)
        #pragma unroll
        for (int nt = 0; nt < 4; nt++)
            #pragma unroll
            for (int i = 0; i < 8; i++) {
                b2[c][nt][i] = f2b(WK2[(c * 32 + g * 8 + i) * 64 + nt * 16 + r]);
                b3[c][nt][i] = f2b(WK3[(c * 32 + g * 8 + i) * 64 + nt * 16 + r]);
            }
    float bdv[2], bkv[2];
    #pragma unroll
    for (int nd = 0; nd < 2; nd++) {
        bdv[nd] = bD[32 + nd * 16 + r];
        bkv[nd] = bencK[nd * 16 + r];
    }
    float bias1[4], bias2[4], bias3[4];
    #pragma unroll
    for (int nt = 0; nt < 4; nt++) {
        bias1[nt] = bK1[nt * 16 + r];
        bias2[nt] = bK2[nt * 16 + r];
        bias3[nt] = bK3[nt * 16 + r];
    }

    const int ntiles = NN / 16;            // 3125 exact
    const int wave = blockIdx.x * 4 + wid;
    const int nw = gridDim.x * 4;
    const f32x4 zero = {0.f, 0.f, 0.f, 0.f};

    for (int tile = wave; tile < ntiles; tile += nw) {
        // A-fragments: xagg rows (nodes), 2 K-chunks
        bf16x8 ax0, ax1;
        {
            const float* xr = xagg + ((size_t)tile * 16 + r) * 64 + g * 8;
            float4 p0 = *reinterpret_cast<const float4*>(xr);
            float4 p1 = *reinterpret_cast<const float4*>(xr + 4);
            float4 p2 = *reinterpret_cast<const float4*>(xr + 32);
            float4 p3 = *reinterpret_cast<const float4*>(xr + 36);
            ax0[0] = f2b(p0.x); ax0[1] = f2b(p0.y); ax0[2] = f2b(p0.z); ax0[3] = f2b(p0.w);
            ax0[4] = f2b(p1.x); ax0[5] = f2b(p1.y); ax0[6] = f2b(p1.z); ax0[7] = f2b(p1.w);
            ax1[0] = f2b(p2.x); ax1[1] = f2b(p2.y); ax1[2] = f2b(p2.z); ax1[3] = f2b(p2.w);
            ax1[4] = f2b(p3.x); ax1[5] = f2b(p3.y); ax1[6] = f2b(p3.z); ax1[7] = f2b(p3.w);
        }
        float cq[4];
        #pragma unroll
        for (int q = 0; q < 4; q++) cq[q] = (float)cnt[tile * 16 + g * 4 + q];

        // dagg = xagg @ WD[:,32:] + cnt*bD[32:]
        f32x4 accd[2];
        #pragma unroll
        for (int nd = 0; nd < 2; nd++) {
            accd[nd] = __builtin_amdgcn_mfma_f32_16x16x32_bf16(ax0, bwd[0][nd], zero, 0, 0, 0);
            accd[nd] = __builtin_amdgcn_mfma_f32_16x16x32_bf16(ax1, bwd[1][nd], accd[nd], 0, 0, 0);
        }
        #pragma unroll
        for (int nd = 0; nd < 2; nd++)
            #pragma unroll
            for (int q = 0; q < 4; q++)
                dagg[((size_t)tile * 16 + g * 4 + q) * 32 + nd * 16 + r] =
                    accd[nd][q] + cq[q] * bdv[nd];

        // hKagg = xagg[:,32:] @ WencK + cnt*bencK  -> LDS transpose (rows=nodes)
        f32x4 acch[2];
        #pragma unroll
        for (int nd = 0; nd < 2; nd++)
            acch[nd] = __builtin_amdgcn_mfma_f32_16x16x32_bf16(ax1, bwk[nd], zero, 0, 0, 0);
        #pragma unroll
        for (int nd = 0; nd < 2; nd++)
            #pragma unroll
            for (int q = 0; q < 4; q++)
                xp[(g * 4 + q) * 68 + nd * 16 + r] = acch[nd][q] + cq[q] * bkv[nd];

        // layer 1 (K=32): A from xp row r
        bf16x8 af;
        #pragma unroll
        for (int i = 0; i < 8; i++) af[i] = f2b(xp[r * 68 + g * 8 + i]);
        f32x4 acc[4];
        #pragma unroll
        for (int nt = 0; nt < 4; nt++)
            acc[nt] = __builtin_amdgcn_mfma_f32_16x16x32_bf16(af, b1[nt], zero, 0, 0, 0);
        #pragma unroll
        for (int nt = 0; nt < 4; nt++)
            #pragma unroll
            for (int q = 0; q < 4; q++)
                xp[(g * 4 + q) * 68 + nt * 16 + r] = fast_tanh(acc[nt][q] + bias1[nt]);

        // layer 2
        f32x4 acc2[4] = {zero, zero, zero, zero};
        #pragma unroll
        for (int c = 0; c < 2; c++) {
            const float* row = xp + r * 68 + c * 32 + g * 8;
            bf16x8 a2;
            #pragma unroll
            for (int i = 0; i < 8; i++) a2[i] = f2b(row[i]);
            #pragma unroll
            for (int nt = 0; nt < 4; nt++)
                acc2[nt] = __builtin_amdgcn_mfma_f32_16x16x32_bf16(a2, b2[c][nt], acc2[nt], 0, 0, 0);
        }
        #pragma unroll
        for (int nt = 0; nt < 4; nt++)
            #pragma unroll
            for (int q = 0; q < 4; q++)
                xp[(g * 4 + q) * 68 + nt * 16 + r] = fmaxf(acc2[nt][q] + bias2[nt], 0.f);

        // layer 3
        f32x4 acc3[4] = {zero, zero, zero, zero};
        #pragma unroll
        for (int c = 0; c < 2; c++) {
            const float* row = xp + r * 68 + c * 32 + g * 8;
            bf16x8 a3;
            #pragma unroll
            for (int i = 0; i < 8; i++) a3[i] = f2b(row[i]);
            #pragma unroll
            for (int nt = 0; nt < 4; nt++)
                acc3[nt] = __builtin_amdgcn_mfma_f32_16x16x32_bf16(a3, b3[c][nt], acc3[nt], 0, 0, 0);
        }
        #pragma unroll
        for (int nt = 0; nt < 4; nt++)
            #pragma unroll
            for (int q = 0; q < 4; q++)
                xp[(g * 4 + q) * 68 + nt * 16 + r] = acc3[nt][q] + bias3[nt];
        {
            const float* row = xp + r * 68 + g * 16;
            unsigned int u[8];
            #pragma unroll
            for (int i = 0; i < 8; i++) u[i] = pack2(row[2 * i], row[2 * i + 1]);
            unsigned int* ob = reinterpret_cast<unsigned int*>(EnodeB + ((size_t)tile * 16 + r) * 64 + g * 16);
            uint4 w0 = {u[0], u[1], u[2], u[3]};
            uint4 w1 = {u[4], u[5], u[6], u[7]};
            *reinterpret_cast<uint4*>(ob) = w0;
            *reinterpret_cast<uint4*>(ob + 4) = w1;
        }
    }
}

// K4 v6 (MFMA, row-stream chunks, prefetched gathers + early Enode fetch,
// carry-merged scatter, setprio).
__global__ void __launch_bounds__(256) k4_mfma(
    const int2* __restrict__ epack,
    const __hip_bfloat16* __restrict__ h1b, const __hip_bfloat16* __restrict__ h2b,
    const __hip_bfloat16* __restrict__ EnodeB, float* __restrict__ Enew,
    const float* __restrict__ WU1, const float* __restrict__ bU1,
    const float* __restrict__ WU2, const float* __restrict__ bU2,
    const float* __restrict__ WU3, const float* __restrict__ bU3)
{
    __shared__ float xpose[4][16 * 68];
    const int wid  = threadIdx.x >> 6;
    const int lane = threadIdx.x & 63;
    const int g = lane >> 4;
    const int r = lane & 15;
    float* xp = xpose[wid];

    bf16x8 b1[4];
    #pragma unroll
    for (int nt = 0; nt < 4; nt++) {
        #pragma unroll
        for (int i = 0; i < 8; i++)
            b1[nt][i] = f2b(WU1[(g * 8 + i) * 64 + nt * 16 + r]);
    }
    bf16x8 b2[2][4], b3[2][4];
    #pragma unroll
    for (int c = 0; c < 2; c++) {
        #pragma unroll
        for (int nt = 0; nt < 4; nt++) {
            #pragma unroll
            for (int i = 0; i < 8; i++) {
                b2[c][nt][i] = f2b(WU2[(c * 32 + g * 8 + i) * 64 + nt * 16 + r]);
                b3[c][nt][i] = f2b(WU3[(c * 32 + g * 8 + i) * 64 + nt * 16 + r]);
            }
        }
    }
    float bias1[4], bias2[4], bias3[4];
    #pragma unroll
    for (int nt = 0; nt < 4; nt++) {
        bias1[nt] = bU1[nt * 16 + r];
        bias2[nt] = bU2[nt * 16 + r];
        bias3[nt] = bU3[nt * 16 + r];
    }

    const int wave = blockIdx.x * 4 + wid;     // [0, K4_WAVES)
    const int base = wave * K4_EPW;
    const f32x4 zero = {0.f, 0.f, 0.f, 0.f};
    const unsigned short* enB = reinterpret_cast<const unsigned short*>(EnodeB);

    int   cd[4] = {-1, -1, -1, -1};
    float cv0[4] = {0, 0, 0, 0}, cv1[4] = {0, 0, 0, 0},
          cv2[4] = {0, 0, 0, 0}, cv3[4] = {0, 0, 0, 0};

    // prefetch t=0
    int2 ep = epack[base + r * K4_C];
    uint4 v1 = *reinterpret_cast<const uint4*>(h1b + (size_t)ep.x * 32 + g * 8);
    uint4 v2 = *reinterpret_cast<const uint4*>(h2b + (size_t)ep.y * 32 + g * 8);

    for (int t = 0; t < K4_C; t++) {
        const int s_me = ep.x, d_me = ep.y;
        union { uint4 v; unsigned int u[4]; } u1, u2;
        u1.v = v1; u2.v = v2;
        // prefetch t+1 (independent -> hides under tile-t compute)
        if (t + 1 < K4_C) {
            ep = epack[base + r * K4_C + t + 1];
            v1 = *reinterpret_cast<const uint4*>(h1b + (size_t)ep.x * 32 + g * 8);
            v2 = *reinterpret_cast<const uint4*>(h2b + (size_t)ep.y * 32 + g * 8);
        }

        // early Enode fetch + dst shuffles for THIS tile (consumed at scatter;
        // latency hides under the MFMA/LDS chain below)
        int dq[4];
        float en0[4], en1[4], en2[4], en3[4];
        #pragma unroll
        for (int q = 0; q < 4; q++) {
            const int er = g * 4 + q;
            const int ssv = __shfl(s_me, er);
            dq[q] = __shfl(d_me, er);
            const unsigned short* enp = enB + (size_t)ssv * 64 + r;
            en0[q] = b2f(enp[0]);
            en1[q] = b2f(enp[16]);
            en2[q] = b2f(enp[32]);
            en3[q] = b2f(enp[48]);
        }

        bf16x8 a;
        #pragma unroll
        for (int w = 0; w < 4; w++) {
            float lo = b2f((unsigned short)(u1.u[w] & 0xffff)) + b2f((unsigned short)(u2.u[w] & 0xffff));
            float hi = b2f((unsigned short)(u1.u[w] >> 16))    + b2f((unsigned short)(u2.u[w] >> 16));
            a[2 * w]     = f2b(lo);
            a[2 * w + 1] = f2b(hi);
        }
        __builtin_amdgcn_s_setprio(1);
        f32x4 acc[4];
        #pragma unroll
        for (int nt = 0; nt < 4; nt++)
            acc[nt] = __builtin_amdgcn_mfma_f32_16x16x32_bf16(a, b1[nt], zero, 0, 0, 0);

        #pragma unroll
        for (int nt = 0; nt < 4; nt++) {
            #pragma unroll
            for (int q = 0; q < 4; q++)
                xp[(g * 4 + q) * 68 + nt * 16 + r] = fast_tanh(acc[nt][q] + bias1[nt]);
        }

        f32x4 acc2[4] = {zero, zero, zero, zero};
        #pragma unroll
        for (int c = 0; c < 2; c++) {
            const float* row = xp + r * 68 + c * 32 + g * 8;
            bf16x8 af;
            #pragma unroll
            for (int i = 0; i < 8; i++) af[i] = f2b(row[i]);
            #pragma unroll
            for (int nt = 0; nt < 4; nt++)
                acc2[nt] = __builtin_amdgcn_mfma_f32_16x16x32_bf16(af, b2[c][nt], acc2[nt], 0, 0, 0);
        }
        #pragma unroll
        for (int nt = 0; nt < 4; nt++) {
            #pragma unroll
            for (int q = 0; q < 4; q++)
                xp[(g * 4 + q) * 68 + nt * 16 + r] = fmaxf(acc2[nt][q] + bias2[nt], 0.f);
        }

        f32x4 acc3[4] = {zero, zero, zero, zero};
        #pragma unroll
        for (int c = 0; c < 2; c++) {
            const float* row = xp + r * 68 + c * 32 + g * 8;
            bf16x8 af;
            #pragma unroll
            for (int i = 0; i < 8; i++) af[i] = f2b(row[i]);
            #pragma unroll
            for (int nt = 0; nt < 4; nt++)
                acc3[nt] = __builtin_amdgcn_mfma_f32_16x16x32_bf16(af, b3[c][nt], acc3[nt], 0, 0, 0);
        }
        __builtin_amdgcn_s_setprio(0);

        #pragma unroll
        for (int q = 0; q < 4; q++) {
            float w0 = (acc3[0][q] + bias3[0]) * en0[q];
            float w1 = (acc3[1][q] + bias3[1]) * en1[q];
            float w2 = (acc3[2][q] + bias3[2]) * en2[q];
            float w3 = (acc3[3][q] + bias3[3]) * en3[q];
            if (dq[q] == cd[q]) {
                cv0[q] += w0; cv1[q] += w1; cv2[q] += w2; cv3[q] += w3;
            } else {
                if (cd[q] >= 0) {
                    float* ew = Enew + (size_t)cd[q] * 64 + r;
                    atomAddF(ew,      cv0[q]);
                    atomAddF(ew + 16, cv1[q]);
                    atomAddF(ew + 32, cv2[q]);
                    atomAddF(ew + 48, cv3[q]);
                }
                cd[q] = dq[q];
                cv0[q] = w0; cv1[q] = w1; cv2[q] = w2; cv3[q] = w3;
            }
        }
    }
    #pragma unroll
    for (int q = 0; q < 4; q++) {
        if (cd[q] >= 0) {
            float* ew = Enew + (size_t)cd[q] * 64 + r;
            atomAddF(ew,      cv0[q]);
            atomAddF(ew + 16, cv1[q]);
            atomAddF(ew + 32, cv2[q]);
            atomAddF(ew + 48, cv3[q]);
        }
    }
}

// K5: dH = E_new @ WH + bH ; out = [dH[:,32:], -dH[:,:32] - dagg]
__global__ void k5_out(const float* __restrict__ Enew, const float* __restrict__ dagg,
                       const float* __restrict__ WH, const float* __restrict__ bH,
                       float* __restrict__ out) {
    int tid = blockIdx.x * blockDim.x + threadIdx.x;
    int n = tid >> 6;
    int j = tid & 63;
    if (n >= NN) return;
    const float* er = Enew + (size_t)n * 64;
    int jj = (j < 32) ? (j + 32) : (j - 32);
    float acc = bH[jj];
    #pragma unroll
    for (int k = 0; k < 64; k++) acc = fmaf(er[k], WH[k * 64 + jj], acc);
    float val;
    if (j < 32) val = acc;
    else        val = -acc - dagg[(size_t)n * 32 + (j - 32)];
    out[tid] = val;
}

extern "C" void kernel_launch(void* const* d_in, const int* in_sizes, int n_in,
                              void* d_out, int out_size, void* d_ws, size_t ws_size,
                              hipStream_t stream) {
    const float* x      = (const float*)d_in[0];
    const int*   src    = (const int*)d_in[1];
    const int*   dst    = (const int*)d_in[2];
    const float* WencK  = (const float*)d_in[3];
    const float* bencK  = (const float*)d_in[4];
    const float* WencP1 = (const float*)d_in[5];
    const float* bencP1 = (const float*)d_in[6];
    const float* WencP2 = (const float*)d_in[7];
    const float* bencP2 = (const float*)d_in[8];
    const float* WK1    = (const float*)d_in[9];
    const float* bK1    = (const float*)d_in[10];
    const float* WK2    = (const float*)d_in[11];
    const float* bK2    = (const float*)d_in[12];
    const float* WK3    = (const float*)d_in[13];
    const float* bK3    = (const float*)d_in[14];
    const float* WU1    = (const float*)d_in[15];
    const float* bU1    = (const float*)d_in[16];
    const float* WU2    = (const float*)d_in[17];
    const float* bU2    = (const float*)d_in[18];
    const float* WU3    = (const float*)d_in[19];
    const float* bU3    = (const float*)d_in[20];
    const float* WH     = (const float*)d_in[21];
    const float* bH     = (const float*)d_in[22];
    const float* WD     = (const float*)d_in[23];
    const float* bD     = (const float*)d_in[24];
    float* out = (float*)d_out;

    // ---- workspace layout (~45.5 MB) ----
    float* buf0 = (float*)d_ws;                                  // NN*64 f32: xagg, later Enew
    float* dagg = buf0 + (size_t)NN * 64;                        // NN*32 f32
    __hip_bfloat16* h1b    = (__hip_bfloat16*)(dagg + (size_t)NN * 32);  // NN*32 bf16
    __hip_bfloat16* h2b    = h1b + (size_t)NN * 32;              // NN*32 bf16
    __hip_bfloat16* EnodeB = h2b + (size_t)NN * 32;              // NN*64 bf16
    __hip_bfloat16* xb     = EnodeB + (size_t)NN * 64;           // NN*64 bf16
    int*  cnt      = (int*)(xb + (size_t)NN * 64);               // NN
    int*  fill     = cnt + NN;                                   // NN
    int*  rowptr   = fill + NN;                                  // NN+2 (pad)
    int*  blocksum = rowptr + NN + 2;                            // 256
    int*  blockoff = blocksum + 256;                             // 256
    int2* epack    = (int2*)(blockoff + 256);                    // EE int2 (8B aligned)
    size_t need = (size_t)NN * 96 * 4 + (size_t)NN * 192 * 2
                + ((size_t)NN * 3 + 2 + 512) * 4 + (size_t)EE * 8;
    if (ws_size < need) return;

    hipMemsetAsync(cnt, 0, (size_t)2 * NN * sizeof(int), stream);           // cnt + fill
    hipMemsetAsync(buf0, 0, (size_t)NN * 64 * sizeof(float), stream);       // xagg

    khist<<<(EE + 255) / 256, 256, 0, stream>>>(dst, cnt);
    kscanA<<<SCAN_NB, 256, 0, stream>>>(cnt, blocksum);
    kscanB<<<1, 256, 0, stream>>>(blocksum, blockoff);
    kscanC<<<SCAN_NB, 256, 0, stream>>>(cnt, blockoff, rowptr);
    kmega1<<<SCAT_BLOCKS + ENC_BLOCKS, 256, 0, stream>>>(
        src, dst, rowptr, fill, epack, x, WencP1, bencP1, WencP2, bencP2, h1b, h2b, xb);
    kxagg3<<<(EE / XA_EPW) / 4, 256, 0, stream>>>(epack, xb, buf0);
    k3ab<<<782, 256, 0, stream>>>(buf0, cnt, WencK, bencK, WD, bD,
                                  WK1, bK1, WK2, bK2, WK3, bK3, dagg, EnodeB);
    // xagg dead -> reuse buf0 as Enew
    hipMemsetAsync(buf0, 0, (size_t)NN * 64 * sizeof(float), stream);
    k4_mfma<<<K4_WAVES / 4, 256, 0, stream>>>(epack, h1b, h2b, EnodeB, buf0,
                                              WU1, bU1, WU2, bU2, WU3, bU3);
    k5_out<<<(NN * 64 + 255) / 256, 256, 0, stream>>>(buf0, dagg, WH, bH, out);
}

// Round 10
// 289.362 us; speedup vs baseline: 1.6056x; 1.0193x over previous
//
#include <hip/hip_runtime.h>
#include <hip/hip_bf16.h>

#define NN 50000
#define EE 800000
#define IN_DIM 64
#define DS_DIM 32
#define HOUT_DIM 64

// k4 chunking: 10000 waves x 80 edges; row r owns stream of C=5 edges.
#define K4_WAVES 10000
#define K4_EPW   80
#define K4_C     5
#define K4_NWG   (K4_WAVES / 4)   // 2500

// kxagg3 chunking: 12500 waves x 64 edges
#define XA_EPW 64
#define XA_NWG 3125

// kmega0 split: first HIST_BLOCKS do histogram, rest do node encoders
#define HIST_BLOCKS 3125   // EE/256
#define ENC_BLOCKS  6250   // NN*32/256

// scan blocks
#define SCAN_NB 196        // ceil(NN/256)

// LDS transpose row stride in bf16 units (144B = 9*16B: even bank spread, 16B-aligned)
#define XPS 72

typedef __attribute__((ext_vector_type(8))) short bf16x8;
typedef __attribute__((ext_vector_type(4))) float f32x4;

__device__ __forceinline__ float fast_tanh(float x) {
    float e = __builtin_amdgcn_exp2f(x * 2.885390082f);
    return 1.f - 2.f * __builtin_amdgcn_rcpf(e + 1.f);
}

__device__ __forceinline__ void atomAddF(float* p, float v) {
#if defined(__AMDGCN__)
    unsafeAtomicAdd(p, v);
#else
    atomicAdd(p, v);
#endif
}

__device__ __forceinline__ short f2b(float f) {
    union { __hip_bfloat16 h; short s; } u;
    u.h = __float2bfloat16(f);
    return u.s;
}
__device__ __forceinline__ float b2f(unsigned short u) {
    return __uint_as_float(((unsigned int)u) << 16);
}

// bijective XCD swizzle (m204): contiguous chunks per XCD, any nwg
__device__ __forceinline__ int xcd_swz(int bid, int nwg) {
    int xcd = bid & 7, idx = bid >> 3;
    int q = nwg >> 3, r = nwg & 7;
    return (xcd < r ? xcd * (q + 1) : r * (q + 1) + (xcd - r) * q) + idx;
}

// KMEGA0: histogram + encoders in one launch (independent work, overlapped).
__global__ void kmega0(const int* __restrict__ dst, int* __restrict__ cnt,
                       const float* __restrict__ x,
                       const float* __restrict__ WencP1, const float* __restrict__ bencP1,
                       const float* __restrict__ WencP2, const float* __restrict__ bencP2,
                       __hip_bfloat16* __restrict__ h1b, __hip_bfloat16* __restrict__ h2b,
                       __hip_bfloat16* __restrict__ xb) {
    if (blockIdx.x < HIST_BLOCKS) {
        int e = blockIdx.x * 256 + threadIdx.x;
        atomicAdd(&cnt[dst[e]], 1);
    } else {
        int tid = (blockIdx.x - HIST_BLOCKS) * 256 + threadIdx.x;
        int n = tid >> 5;
        int j = tid & 31;
        if (n >= NN) return;
        const float* xr = x + (size_t)n * IN_DIM;
        float a1 = bencP1[j], a2 = bencP2[j];
        #pragma unroll
        for (int k = 0; k < 32; k++) {
            float q = xr[k];
            a1 = fmaf(q, WencP1[k * 32 + j], a1);
            a2 = fmaf(q, WencP2[k * 32 + j], a2);
        }
        union { __hip_bfloat16 h; short s; } u1, u2, u3, u4;
        u1.s = f2b(a1); u2.s = f2b(a2);
        h1b[(size_t)n * 32 + j] = u1.h;
        h2b[(size_t)n * 32 + j] = u2.h;
        u3.s = f2b(xr[j]); u4.s = f2b(xr[32 + j]);
        xb[(size_t)n * 64 + j] = u3.h;
        xb[(size_t)n * 64 + 32 + j] = u4.h;
    }
}

// 3-phase coalesced exclusive scan of cnt[NN] -> rowptr[NN+1]
__global__ void kscanA(const int* __restrict__ cnt, int* __restrict__ blocksum) {
    __shared__ int s[256];
    int t = threadIdx.x;
    int i = blockIdx.x * 256 + t;
    s[t] = (i < NN) ? cnt[i] : 0;
    __syncthreads();
    #pragma unroll
    for (int off = 128; off > 0; off >>= 1) {
        if (t < off) s[t] += s[t + off];
        __syncthreads();
    }
    if (t == 0) blocksum[blockIdx.x] = s[0];
}

__global__ void kscanB(const int* __restrict__ blocksum, int* __restrict__ blockoff) {
    __shared__ int part[256];
    int t = threadIdx.x;
    int v = (t < SCAN_NB) ? blocksum[t] : 0;
    part[t] = v;
    __syncthreads();
    for (int off = 1; off < 256; off <<= 1) {
        int u = (t >= off) ? part[t - off] : 0;
        __syncthreads();
        part[t] += u;
        __syncthreads();
    }
    if (t < SCAN_NB) blockoff[t] = part[t] - v;  // exclusive
}

__global__ void kscanC(const int* __restrict__ cnt, const int* __restrict__ blockoff,
                       int* __restrict__ rowptr) {
    __shared__ int part[256];
    int t = threadIdx.x;
    int i = blockIdx.x * 256 + t;
    int v = (i < NN) ? cnt[i] : 0;
    part[t] = v;
    __syncthreads();
    for (int off = 1; off < 256; off <<= 1) {
        int u = (t >= off) ? part[t - off] : 0;
        __syncthreads();
        part[t] += u;
        __syncthreads();
    }
    if (i < NN) {
        int incl = blockoff[blockIdx.x] + part[t];
        rowptr[i] = incl - v;
        if (i == NN - 1) rowptr[NN] = incl;
    }
}

// KSCATTER: place edges into dst-sorted int2 list, rank via atomic fill.
__global__ void kscatter(const int* __restrict__ src, const int* __restrict__ dst,
                         const int* __restrict__ rowptr, int* __restrict__ fill,
                         int2* __restrict__ epack) {
    int e = blockIdx.x * 256 + threadIdx.x;
    if (e >= EE) return;
    int d = dst[e];
    int pos = rowptr[d] + atomicAdd(&fill[d], 1);
    int2 p; p.x = src[e]; p.y = d;
    epack[pos] = p;
}

// KXAGG3: edge-chunk carry-merged segment-sum of bf16 x rows into xagg (f32).
__global__ void __launch_bounds__(256) kxagg3(const int2* __restrict__ epack,
                                              const __hip_bfloat16* __restrict__ xb,
                                              float* __restrict__ xagg) {
    int sbid = xcd_swz(blockIdx.x, XA_NWG);
    int w = sbid * 4 + (threadIdx.x >> 6);
    int lane = threadIdx.x & 63;
    int base = w * XA_EPW;
    const unsigned short* xu = reinterpret_cast<const unsigned short*>(xb);

    int2 myep = epack[base + lane];     // coalesced 512B per wave
    int sarr = myep.x, darr = myep.y;

    float v0 = b2f(xu[(size_t)__shfl(sarr, 0) * 64 + lane]);
    float v1 = b2f(xu[(size_t)__shfl(sarr, 1) * 64 + lane]);
    float v2 = b2f(xu[(size_t)__shfl(sarr, 2) * 64 + lane]);
    float v3 = b2f(xu[(size_t)__shfl(sarr, 3) * 64 + lane]);
    int cd = __shfl(darr, 0);
    float carry = 0.f;

#define XA_STEP(vv, T)                                                        \
    {                                                                         \
        float cur = vv;                                                       \
        if ((T) + 4 < XA_EPW)                                                 \
            vv = b2f(xu[(size_t)__shfl(sarr, (T) + 4) * 64 + lane]);          \
        int d = __shfl(darr, (T));                                            \
        if (d != cd) {                                                        \
            atomAddF(&xagg[(size_t)cd * 64 + lane], carry);                   \
            cd = d; carry = 0.f;                                              \
        }                                                                     \
        carry += cur;                                                         \
    }

    for (int tb = 0; tb < XA_EPW; tb += 4) {
        XA_STEP(v0, tb);
        XA_STEP(v1, tb + 1);
        XA_STEP(v2, tb + 2);
        XA_STEP(v3, tb + 3);
    }
#undef XA_STEP
    atomAddF(&xagg[(size_t)cd * 64 + lane], carry);
}

// K3AB (fused): dagg (MFMA) + hKagg (MFMA, bf16 LDS) + 3-layer node MLP -> EnodeB.
__global__ void __launch_bounds__(256) k3ab(
    const float* __restrict__ xagg, const int* __restrict__ cnt,
    const float* __restrict__ WencK, const float* __restrict__ bencK,
    const float* __restrict__ WD, const float* __restrict__ bD,
    const float* __restrict__ WK1, const float* __restrict__ bK1,
    const float* __restrict__ WK2, const float* __restrict__ bK2,
    const float* __restrict__ WK3, const float* __restrict__ bK3,
    float* __restrict__ dagg, __hip_bfloat16* __restrict__ EnodeB)
{
    __shared__ unsigned short xpose[4][16 * XPS];
    const int wid  = threadIdx.x >> 6;
    const int lane = threadIdx.x & 63;
    const int g = lane >> 4;
    const int r = lane & 15;
    unsigned short* xp = xpose[wid];

    bf16x8 bwd[2][2];
    #pragma unroll
    for (int c = 0; c < 2; c++)
        #pragma unroll
        for (int nd = 0; nd < 2; nd++)
            #pragma unroll
            for (int i = 0; i < 8; i++)
                bwd[c][nd][i] = f2b(WD[(c * 32 + g * 8 + i) * 64 + 32 + nd * 16 + r]);
    bf16x8 bwk[2];
    #pragma unroll
    for (int nd = 0; nd < 2; nd++)
        #pragma unroll
        for (int i = 0; i < 8; i++)
            bwk[nd][i] = f2b(WencK[(g * 8 + i) * 32 + nd * 16 + r]);
    bf16x8 b1[4];
    #pragma unroll
    for (int nt = 0; nt < 4; nt++)
        #pragma unroll
        for (int i = 0; i < 8; i++)
            b1[nt][i] = f2b(WK1[(g * 8 + i) * 64 + nt * 16 + r]);
    bf16x8 b2[2][4], b3[2][4];
    #pragma unroll
    for (int c = 0; c < 2; c++)
        #pragma unroll
        for (int nt = 0; nt < 4; nt++)
            #pragma unroll
            for (int i = 0; i < 8; i++) {
                b2[c][nt][i] = f2b(WK2[(c * 32 + g * 8 + i) * 64 + nt * 16 + r]);
                b3[c][nt][i] = f2b(WK3[(c * 32 + g * 8 + i) * 64 + nt * 16 + r]);
            }
    float bdv[2], bkv[2];
    #pragma unroll
    for (int nd = 0; nd < 2; nd++) {
        bdv[nd] = bD[32 + nd * 16 + r];
        bkv[nd] = bencK[nd * 16 + r];
    }
    float bias1[4], bias2[4], bias3[4];
    #pragma unroll
    for (int nt = 0; nt < 4; nt++) {
        bias1[nt] = bK1[nt * 16 + r];
        bias2[nt] = bK2[nt * 16 + r];
        bias3[nt] = bK3[nt * 16 + r];
    }

    const int ntiles = NN / 16;            // 3125 exact
    const int wave = blockIdx.x * 4 + wid;
    const int nw = gridDim.x * 4;
    const f32x4 zero = {0.f, 0.f, 0.f, 0.f};

    for (int tile = wave; tile < ntiles; tile += nw) {
        bf16x8 ax0, ax1;
        {
            const float* xr = xagg + ((size_t)tile * 16 + r) * 64 + g * 8;
            float4 p0 = *reinterpret_cast<const float4*>(xr);
            float4 p1 = *reinterpret_cast<const float4*>(xr + 4);
            float4 p2 = *reinterpret_cast<const float4*>(xr + 32);
            float4 p3 = *reinterpret_cast<const float4*>(xr + 36);
            ax0[0] = f2b(p0.x); ax0[1] = f2b(p0.y); ax0[2] = f2b(p0.z); ax0[3] = f2b(p0.w);
            ax0[4] = f2b(p1.x); ax0[5] = f2b(p1.y); ax0[6] = f2b(p1.z); ax0[7] = f2b(p1.w);
            ax1[0] = f2b(p2.x); ax1[1] = f2b(p2.y); ax1[2] = f2b(p2.z); ax1[3] = f2b(p2.w);
            ax1[4] = f2b(p3.x); ax1[5] = f2b(p3.y); ax1[6] = f2b(p3.z); ax1[7] = f2b(p3.w);
        }
        float cq[4];
        #pragma unroll
        for (int q = 0; q < 4; q++) cq[q] = (float)cnt[tile * 16 + g * 4 + q];

        // dagg
        f32x4 accd[2];
        #pragma unroll
        for (int nd = 0; nd < 2; nd++) {
            accd[nd] = __builtin_amdgcn_mfma_f32_16x16x32_bf16(ax0, bwd[0][nd], zero, 0, 0, 0);
            accd[nd] = __builtin_amdgcn_mfma_f32_16x16x32_bf16(ax1, bwd[1][nd], accd[nd], 0, 0, 0);
        }
        #pragma unroll
        for (int nd = 0; nd < 2; nd++)
            #pragma unroll
            for (int q = 0; q < 4; q++)
                dagg[((size_t)tile * 16 + g * 4 + q) * 32 + nd * 16 + r] =
                    accd[nd][q] + cq[q] * bdv[nd];

        // hKagg -> bf16 LDS (rows = nodes)
        f32x4 acch[2];
        #pragma unroll
        for (int nd = 0; nd < 2; nd++)
            acch[nd] = __builtin_amdgcn_mfma_f32_16x16x32_bf16(ax1, bwk[nd], zero, 0, 0, 0);
        #pragma unroll
        for (int nd = 0; nd < 2; nd++)
            #pragma unroll
            for (int q = 0; q < 4; q++)
                xp[(g * 4 + q) * XPS + nd * 16 + r] = (unsigned short)f2b(acch[nd][q] + cq[q] * bkv[nd]);

        // layer 1 (K=32)
        bf16x8 af = *reinterpret_cast<const bf16x8*>(xp + r * XPS + g * 8);
        f32x4 acc[4];
        #pragma unroll
        for (int nt = 0; nt < 4; nt++)
            acc[nt] = __builtin_amdgcn_mfma_f32_16x16x32_bf16(af, b1[nt], zero, 0, 0, 0);
        #pragma unroll
        for (int nt = 0; nt < 4; nt++)
            #pragma unroll
            for (int q = 0; q < 4; q++)
                xp[(g * 4 + q) * XPS + nt * 16 + r] = (unsigned short)f2b(fast_tanh(acc[nt][q] + bias1[nt]));

        // layer 2
        f32x4 acc2[4] = {zero, zero, zero, zero};
        #pragma unroll
        for (int c = 0; c < 2; c++) {
            bf16x8 a2 = *reinterpret_cast<const bf16x8*>(xp + r * XPS + c * 32 + g * 8);
            #pragma unroll
            for (int nt = 0; nt < 4; nt++)
                acc2[nt] = __builtin_amdgcn_mfma_f32_16x16x32_bf16(a2, b2[c][nt], acc2[nt], 0, 0, 0);
        }
        #pragma unroll
        for (int nt = 0; nt < 4; nt++)
            #pragma unroll
            for (int q = 0; q < 4; q++)
                xp[(g * 4 + q) * XPS + nt * 16 + r] = (unsigned short)f2b(fmaxf(acc2[nt][q] + bias2[nt], 0.f));

        // layer 3
        f32x4 acc3[4] = {zero, zero, zero, zero};
        #pragma unroll
        for (int c = 0; c < 2; c++) {
            bf16x8 a3 = *reinterpret_cast<const bf16x8*>(xp + r * XPS + c * 32 + g * 8);
            #pragma unroll
            for (int nt = 0; nt < 4; nt++)
                acc3[nt] = __builtin_amdgcn_mfma_f32_16x16x32_bf16(a3, b3[c][nt], acc3[nt], 0, 0, 0);
        }
        #pragma unroll
        for (int nt = 0; nt < 4; nt++)
            #pragma unroll
            for (int q = 0; q < 4; q++)
                xp[(g * 4 + q) * XPS + nt * 16 + r] = (unsigned short)f2b(acc3[nt][q] + bias3[nt]);
        {
            uint4 w0 = *reinterpret_cast<const uint4*>(xp + r * XPS + g * 16);
            uint4 w1 = *reinterpret_cast<const uint4*>(xp + r * XPS + g * 16 + 8);
            unsigned int* ob = reinterpret_cast<unsigned int*>(EnodeB + ((size_t)tile * 16 + r) * 64 + g * 16);
            *reinterpret_cast<uint4*>(ob) = w0;
            *reinterpret_cast<uint4*>(ob + 4) = w1;
        }
    }
}

// K4 v7 (MFMA, bf16 LDS transposes, prefetched gathers + early Enode fetch,
// carry-merged scatter, setprio, XCD swizzle).
__global__ void __launch_bounds__(256) k4_mfma(
    const int2* __restrict__ epack,
    const __hip_bfloat16* __restrict__ h1b, const __hip_bfloat16* __restrict__ h2b,
    const __hip_bfloat16* __restrict__ EnodeB, float* __restrict__ Enew,
    const float* __restrict__ WU1, const float* __restrict__ bU1,
    const float* __restrict__ WU2, const float* __restrict__ bU2,
    const float* __restrict__ WU3, const float* __restrict__ bU3)
{
    __shared__ unsigned short xpose[4][16 * XPS];
    const int wid  = threadIdx.x >> 6;
    const int lane = threadIdx.x & 63;
    const int g = lane >> 4;
    const int r = lane & 15;
    unsigned short* xp = xpose[wid];

    bf16x8 b1[4];
    #pragma unroll
    for (int nt = 0; nt < 4; nt++) {
        #pragma unroll
        for (int i = 0; i < 8; i++)
            b1[nt][i] = f2b(WU1[(g * 8 + i) * 64 + nt * 16 + r]);
    }
    bf16x8 b2[2][4], b3[2][4];
    #pragma unroll
    for (int c = 0; c < 2; c++) {
        #pragma unroll
        for (int nt = 0; nt < 4; nt++) {
            #pragma unroll
            for (int i = 0; i < 8; i++) {
                b2[c][nt][i] = f2b(WU2[(c * 32 + g * 8 + i) * 64 + nt * 16 + r]);
                b3[c][nt][i] = f2b(WU3[(c * 32 + g * 8 + i) * 64 + nt * 16 + r]);
            }
        }
    }
    float bias1[4], bias2[4], bias3[4];
    #pragma unroll
    for (int nt = 0; nt < 4; nt++) {
        bias1[nt] = bU1[nt * 16 + r];
        bias2[nt] = bU2[nt * 16 + r];
        bias3[nt] = bU3[nt * 16 + r];
    }

    const int sbid = xcd_swz(blockIdx.x, K4_NWG);
    const int wave = sbid * 4 + wid;           // [0, K4_WAVES)
    const int base = wave * K4_EPW;
    const f32x4 zero = {0.f, 0.f, 0.f, 0.f};
    const unsigned short* enB = reinterpret_cast<const unsigned short*>(EnodeB);

    int   cd[4] = {-1, -1, -1, -1};
    float cv0[4] = {0, 0, 0, 0}, cv1[4] = {0, 0, 0, 0},
          cv2[4] = {0, 0, 0, 0}, cv3[4] = {0, 0, 0, 0};

    // prefetch t=0
    int2 ep = epack[base + r * K4_C];
    uint4 v1 = *reinterpret_cast<const uint4*>(h1b + (size_t)ep.x * 32 + g * 8);
    uint4 v2 = *reinterpret_cast<const uint4*>(h2b + (size_t)ep.y * 32 + g * 8);

    for (int t = 0; t < K4_C; t++) {
        const int s_me = ep.x, d_me = ep.y;
        union { uint4 v; unsigned int u[4]; } u1, u2;
        u1.v = v1; u2.v = v2;
        if (t + 1 < K4_C) {
            ep = epack[base + r * K4_C + t + 1];
            v1 = *reinterpret_cast<const uint4*>(h1b + (size_t)ep.x * 32 + g * 8);
            v2 = *reinterpret_cast<const uint4*>(h2b + (size_t)ep.y * 32 + g * 8);
        }

        // early Enode fetch + dst shuffles (consumed at scatter)
        int dq[4];
        float en0[4], en1[4], en2[4], en3[4];
        #pragma unroll
        for (int q = 0; q < 4; q++) {
            const int er = g * 4 + q;
            const int ssv = __shfl(s_me, er);
            dq[q] = __shfl(d_me, er);
            const unsigned short* enp = enB + (size_t)ssv * 64 + r;
            en0[q] = b2f(enp[0]);
            en1[q] = b2f(enp[16]);
            en2[q] = b2f(enp[32]);
            en3[q] = b2f(enp[48]);
        }

        bf16x8 a;
        #pragma unroll
        for (int w = 0; w < 4; w++) {
            float lo = b2f((unsigned short)(u1.u[w] & 0xffff)) + b2f((unsigned short)(u2.u[w] & 0xffff));
            float hi = b2f((unsigned short)(u1.u[w] >> 16))    + b2f((unsigned short)(u2.u[w] >> 16));
            a[2 * w]     = f2b(lo);
            a[2 * w + 1] = f2b(hi);
        }
        __builtin_amdgcn_s_setprio(1);
        f32x4 acc[4];
        #pragma unroll
        for (int nt = 0; nt < 4; nt++)
            acc[nt] = __builtin_amdgcn_mfma_f32_16x16x32_bf16(a, b1[nt], zero, 0, 0, 0);

        #pragma unroll
        for (int nt = 0; nt < 4; nt++) {
            #pragma unroll
            for (int q = 0; q < 4; q++)
                xp[(g * 4 + q) * XPS + nt * 16 + r] = (unsigned short)f2b(fast_tanh(acc[nt][q] + bias1[nt]));
        }

        f32x4 acc2[4] = {zero, zero, zero, zero};
        #pragma unroll
        for (int c = 0; c < 2; c++) {
            bf16x8 af = *reinterpret_cast<const bf16x8*>(xp + r * XPS + c * 32 + g * 8);
            #pragma unroll
            for (int nt = 0; nt < 4; nt++)
                acc2[nt] = __builtin_amdgcn_mfma_f32_16x16x32_bf16(af, b2[c][nt], acc2[nt], 0, 0, 0);
        }
        #pragma unroll
        for (int nt = 0; nt < 4; nt++) {
            #pragma unroll
            for (int q = 0; q < 4; q++)
                xp[(g * 4 + q) * XPS + nt * 16 + r] = (unsigned short)f2b(fmaxf(acc2[nt][q] + bias2[nt], 0.f));
        }

        f32x4 acc3[4] = {zero, zero, zero, zero};
        #pragma unroll
        for (int c = 0; c < 2; c++) {
            bf16x8 af = *reinterpret_cast<const bf16x8*>(xp + r * XPS + c * 32 + g * 8);
            #pragma unroll
            for (int nt = 0; nt < 4; nt++)
                acc3[nt] = __builtin_amdgcn_mfma_f32_16x16x32_bf16(af, b3[c][nt], acc3[nt], 0, 0, 0);
        }
        __builtin_amdgcn_s_setprio(0);

        #pragma unroll
        for (int q = 0; q < 4; q++) {
            float w0 = (acc3[0][q] + bias3[0]) * en0[q];
            float w1 = (acc3[1][q] + bias3[1]) * en1[q];
            float w2 = (acc3[2][q] + bias3[2]) * en2[q];
            float w3 = (acc3[3][q] + bias3[3]) * en3[q];
            if (dq[q] == cd[q]) {
                cv0[q] += w0; cv1[q] += w1; cv2[q] += w2; cv3[q] += w3;
            } else {
                if (cd[q] >= 0) {
                    float* ew = Enew + (size_t)cd[q] * 64 + r;
                    atomAddF(ew,      cv0[q]);
                    atomAddF(ew + 16, cv1[q]);
                    atomAddF(ew + 32, cv2[q]);
                    atomAddF(ew + 48, cv3[q]);
                }
                cd[q] = dq[q];
                cv0[q] = w0; cv1[q] = w1; cv2[q] = w2; cv3[q] = w3;
            }
        }
    }
    #pragma unroll
    for (int q = 0; q < 4; q++) {
        if (cd[q] >= 0) {
            float* ew = Enew + (size_t)cd[q] * 64 + r;
            atomAddF(ew,      cv0[q]);
            atomAddF(ew + 16, cv1[q]);
            atomAddF(ew + 32, cv2[q]);
            atomAddF(ew + 48, cv3[q]);
        }
    }
}

// K5: dH = E_new @ WH + bH ; out = [dH[:,32:], -dH[:,:32] - dagg]
__global__ void k5_out(const float* __restrict__ Enew, const float* __restrict__ dagg,
                       const float* __restrict__ WH, const float* __restrict__ bH,
                       float* __restrict__ out) {
    int tid = blockIdx.x * blockDim.x + threadIdx.x;
    int n = tid >> 6;
    int j = tid & 63;
    if (n >= NN) return;
    const float* er = Enew + (size_t)n * 64;
    int jj = (j < 32) ? (j + 32) : (j - 32);
    float acc = bH[jj];
    #pragma unroll
    for (int k = 0; k < 64; k++) acc = fmaf(er[k], WH[k * 64 + jj], acc);
    float val;
    if (j < 32) val = acc;
    else        val = -acc - dagg[(size_t)n * 32 + (j - 32)];
    out[tid] = val;
}

extern "C" void kernel_launch(void* const* d_in, const int* in_sizes, int n_in,
                              void* d_out, int out_size, void* d_ws, size_t ws_size,
                              hipStream_t stream) {
    const float* x      = (const float*)d_in[0];
    const int*   src    = (const int*)d_in[1];
    const int*   dst    = (const int*)d_in[2];
    const float* WencK  = (const float*)d_in[3];
    const float* bencK  = (const float*)d_in[4];
    const float* WencP1 = (const float*)d_in[5];
    const float* bencP1 = (const float*)d_in[6];
    const float* WencP2 = (const float*)d_in[7];
    const float* bencP2 = (const float*)d_in[8];
    const float* WK1    = (const float*)d_in[9];
    const float* bK1    = (const float*)d_in[10];
    const float* WK2    = (const float*)d_in[11];
    const float* bK2    = (const float*)d_in[12];
    const float* WK3    = (const float*)d_in[13];
    const float* bK3    = (const float*)d_in[14];
    const float* WU1    = (const float*)d_in[15];
    const float* bU1    = (const float*)d_in[16];
    const float* WU2    = (const float*)d_in[17];
    const float* bU2    = (const float*)d_in[18];
    const float* WU3    = (const float*)d_in[19];
    const float* bU3    = (const float*)d_in[20];
    const float* WH     = (const float*)d_in[21];
    const float* bH     = (const float*)d_in[22];
    const float* WD     = (const float*)d_in[23];
    const float* bD     = (const float*)d_in[24];
    float* out = (float*)d_out;

    // ---- workspace layout (~58.3 MB) ----
    float* xagg = (float*)d_ws;                                  // NN*64 f32
    float* Enew = xagg + (size_t)NN * 64;                        // NN*64 f32 (adjacent: one memset)
    float* dagg = Enew + (size_t)NN * 64;                        // NN*32 f32
    __hip_bfloat16* h1b    = (__hip_bfloat16*)(dagg + (size_t)NN * 32);  // NN*32 bf16
    __hip_bfloat16* h2b    = h1b + (size_t)NN * 32;              // NN*32 bf16
    __hip_bfloat16* EnodeB = h2b + (size_t)NN * 32;              // NN*64 bf16
    __hip_bfloat16* xb     = EnodeB + (size_t)NN * 64;           // NN*64 bf16
    int*  cnt      = (int*)(xb + (size_t)NN * 64);               // NN
    int*  fill     = cnt + NN;                                   // NN
    int*  rowptr   = fill + NN;                                  // NN+2 (pad)
    int*  blocksum = rowptr + NN + 2;                            // 256
    int*  blockoff = blocksum + 256;                             // 256
    int2* epack    = (int2*)(blockoff + 256);                    // EE int2 (8B aligned)
    size_t need = (size_t)NN * 160 * 4 + (size_t)NN * 192 * 2
                + ((size_t)NN * 3 + 2 + 512) * 4 + (size_t)EE * 8;
    if (ws_size < need) return;

    // all zero-init up front (no mid-pipeline bubbles)
    hipMemsetAsync(cnt, 0, (size_t)2 * NN * sizeof(int), stream);           // cnt + fill
    hipMemsetAsync(xagg, 0, (size_t)NN * 128 * sizeof(float), stream);      // xagg + Enew

    kmega0<<<HIST_BLOCKS + ENC_BLOCKS, 256, 0, stream>>>(
        dst, cnt, x, WencP1, bencP1, WencP2, bencP2, h1b, h2b, xb);
    kscanA<<<SCAN_NB, 256, 0, stream>>>(cnt, blocksum);
    kscanB<<<1, 256, 0, stream>>>(blocksum, blockoff);
    kscanC<<<SCAN_NB, 256, 0, stream>>>(cnt, blockoff, rowptr);
    kscatter<<<HIST_BLOCKS, 256, 0, stream>>>(src, dst, rowptr, fill, epack);
    kxagg3<<<XA_NWG, 256, 0, stream>>>(epack, xb, xagg);
    k3ab<<<782, 256, 0, stream>>>(xagg, cnt, WencK, bencK, WD, bD,
                                  WK1, bK1, WK2, bK2, WK3, bK3, dagg, EnodeB);
    k4_mfma<<<K4_NWG, 256, 0, stream>>>(epack, h1b, h2b, EnodeB, Enew,
                                        WU1, bU1, WU2, bU2, WU3, bU3);
    k5_out<<<(NN * 64 + 255) / 256, 256, 0, stream>>>(Enew, dagg, WH, bH, out);
}